// Round 3
// baseline (1201.944 us; speedup 1.0000x reference)
//
#include <hip/hip_runtime.h>
#include <math.h>

// ---------------- problem constants ----------------
constexpr int T_ = 2048;   // tokens (B*S)
constexpr int D_ = 1024;   // model dim
constexpr int E_ = 16;     // experts
constexpr int H_ = 1024;   // expert hidden
constexpr int K_ = 4;      // top-k
constexpr float EPS_ = 1e-6f;

// ---------------- GEMM tiling ----------------
constexpr int BM = 128, BN = 128, BK = 16;
constexpr int MT_TILES = T_ / BM;   // 16 (worst case: all tokens to one expert)
constexpr int NT1 = H_ / BN;        // 8
constexpr int NT2 = D_ / BN;        // 8

// ---------------- workspace layout (bytes) ----------------
constexpr size_t WS_CNT   = 0;                                  // E ints (zeroed each launch)
constexpr size_t WS_LISTP = 256;                                // E*T ints: pair index p = t*4+k
constexpr size_t WS_LISTW = WS_LISTP + (size_t)E_ * T_ * 4;     // E*T floats: combine weight
constexpr size_t WS_NSC   = WS_LISTW + (size_t)E_ * T_ * 4;     // T*E floats: normalized scores
constexpr size_t WS_ABUF  = WS_NSC  + (size_t)T_ * E_ * 4;      // T*K*H floats: a = silu(h)*g
// total ≈ 34 MB

__device__ __forceinline__ float silu_f(float h) {
    return h / (1.f + expf(-h));   // h * sigmoid(h)
}

// ================= router =================
// one block per token: logits = x@gate_w + bias; sigmoid; normalize; top-4;
// renormalize weights; atomic slot assignment into per-expert pair lists.
__global__ __launch_bounds__(256) void router_kernel(
    const float* __restrict__ x, const float* __restrict__ gw,
    const float* __restrict__ bias,
    int* __restrict__ cnt, float* __restrict__ nsc,
    int* __restrict__ list_p, float* __restrict__ list_w)
{
    const int t = blockIdx.x;
    const int tid = threadIdx.x;

    float part[E_];
#pragma unroll
    for (int e = 0; e < E_; ++e) part[e] = 0.f;

    const float* xr = x + (size_t)t * D_;
    for (int it = 0; it < D_ / 256; ++it) {
        int d = it * 256 + tid;
        float xv = xr[d];
        const float4* g4 = reinterpret_cast<const float4*>(gw + (size_t)d * E_);
#pragma unroll
        for (int q = 0; q < 4; ++q) {
            float4 gv = g4[q];
            part[q * 4 + 0] += xv * gv.x;
            part[q * 4 + 1] += xv * gv.y;
            part[q * 4 + 2] += xv * gv.z;
            part[q * 4 + 3] += xv * gv.w;
        }
    }
    // wave (64-lane) shuffle reduce, then cross-wave via LDS
#pragma unroll
    for (int e = 0; e < E_; ++e) {
        float v = part[e];
#pragma unroll
        for (int off = 32; off > 0; off >>= 1) v += __shfl_down(v, off);
        part[e] = v;
    }
    __shared__ float red[4 * E_];
    const int wave = tid >> 6, lane = tid & 63;
    if (lane == 0) {
#pragma unroll
        for (int e = 0; e < E_; ++e) red[wave * E_ + e] = part[e];
    }
    __syncthreads();

    __shared__ float sc[E_];
    if (tid < E_) {
        float s = red[0 * E_ + tid] + red[1 * E_ + tid] + red[2 * E_ + tid] + red[3 * E_ + tid];
        s += bias[tid];
        sc[tid] = 1.f / (1.f + expf(-s));   // sigmoid
    }
    __syncthreads();

    if (tid == 0) {
        float sum = 0.f;
#pragma unroll
        for (int e = 0; e < E_; ++e) sum += sc[e];
        float den = sum + EPS_;
        float ns[E_];
#pragma unroll
        for (int e = 0; e < E_; ++e) {
            ns[e] = sc[e] / den;
            nsc[(size_t)t * E_ + e] = ns[e];   // for lb_loss (avg over tokens)
        }
        // serial top-4, ties -> lowest index (matches jax.lax.top_k)
        bool used[E_];
#pragma unroll
        for (int e = 0; e < E_; ++e) used[e] = false;
        int sel[K_]; float selw[K_]; float wsum = 0.f;
        for (int k = 0; k < K_; ++k) {
            float best = -1.f; int bi = 0;
            for (int e = 0; e < E_; ++e)
                if (!used[e] && ns[e] > best) { best = ns[e]; bi = e; }
            used[bi] = true; sel[k] = bi; selw[k] = best; wsum += best;
        }
        float wden = wsum + EPS_;
        for (int k = 0; k < K_; ++k) {
            int e = sel[k];
            int slot = atomicAdd(&cnt[e], 1);
            list_p[(size_t)e * T_ + slot] = t * K_ + k;
            list_w[(size_t)e * T_ + slot] = selw[k] / wden;
        }
    }
}

// ================= GEMM1: a = silu(x@w1) * (x@w3), grouped by expert =================
__global__ __launch_bounds__(256) void gemm1_kernel(
    const float* __restrict__ x, const float* __restrict__ w1,
    const float* __restrict__ w3, const int* __restrict__ cnt,
    const int* __restrict__ list_p, float* __restrict__ a_buf)
{
    const int bid = blockIdx.x;
    const int e   = bid / (MT_TILES * NT1);
    const int rem = bid % (MT_TILES * NT1);
    const int mt  = rem / NT1;
    const int nt  = rem % NT1;
    const int ne  = cnt[e];
    if (mt * BM >= ne) return;          // early-exit: static worst-case grid
    const int n0  = nt * BN;
    const int tid = threadIdx.x;

    __shared__ int   ps[BM];
    __shared__ int   ts[BM];
    __shared__ float xs[BK][BM + 4];    // transposed x tile; +4 pad keeps rows 16B-aligned
    __shared__ float w1s[BK][BN + 4];
    __shared__ float w3s[BK][BN + 4];

    if (tid < BM) {
        int slot = mt * BM + tid;
        if (slot < ne) { int p = list_p[(size_t)e * T_ + slot]; ps[tid] = p; ts[tid] = p >> 2; }
        else           { ps[tid] = -1; ts[tid] = 0; }
    }
    __syncthreads();

    float acch[8][8], accg[8][8];
#pragma unroll
    for (int i = 0; i < 8; ++i)
#pragma unroll
        for (int j = 0; j < 8; ++j) { acch[i][j] = 0.f; accg[i][j] = 0.f; }

    const int ty = tid >> 4, tx = tid & 15;
    const int mrow = tid >> 1, mq = tid & 1;    // x staging: 2 float4 per thread
    const int wkk = tid >> 4,  wc4 = tid & 15;  // w staging
    const int xrow = ts[mrow];

    for (int k0 = 0; k0 < D_; k0 += BK) {
        const float4* xsrc = reinterpret_cast<const float4*>(x + (size_t)xrow * D_ + k0 + mq * 8);
        float4 xv0 = xsrc[0];
        float4 xv1 = xsrc[1];
        const float* b1p = w1 + ((size_t)e * D_ + k0 + wkk) * H_ + n0;
        const float* b3p = w3 + ((size_t)e * D_ + k0 + wkk) * H_ + n0;
        float4 bA = *reinterpret_cast<const float4*>(b1p + wc4 * 4);
        float4 bB = *reinterpret_cast<const float4*>(b1p + wc4 * 4 + 64);
        float4 cA = *reinterpret_cast<const float4*>(b3p + wc4 * 4);
        float4 cB = *reinterpret_cast<const float4*>(b3p + wc4 * 4 + 64);

        xs[mq * 8 + 0][mrow] = xv0.x; xs[mq * 8 + 1][mrow] = xv0.y;
        xs[mq * 8 + 2][mrow] = xv0.z; xs[mq * 8 + 3][mrow] = xv0.w;
        xs[mq * 8 + 4][mrow] = xv1.x; xs[mq * 8 + 5][mrow] = xv1.y;
        xs[mq * 8 + 6][mrow] = xv1.z; xs[mq * 8 + 7][mrow] = xv1.w;
        *reinterpret_cast<float4*>(&w1s[wkk][wc4 * 4])      = bA;
        *reinterpret_cast<float4*>(&w1s[wkk][wc4 * 4 + 64]) = bB;
        *reinterpret_cast<float4*>(&w3s[wkk][wc4 * 4])      = cA;
        *reinterpret_cast<float4*>(&w3s[wkk][wc4 * 4 + 64]) = cB;
        __syncthreads();

#pragma unroll
        for (int k = 0; k < BK; ++k) {
            float4 a0 = *reinterpret_cast<const float4*>(&xs[k][ty * 4]);
            float4 a1 = *reinterpret_cast<const float4*>(&xs[k][64 + ty * 4]);
            float4 u0 = *reinterpret_cast<const float4*>(&w1s[k][tx * 4]);
            float4 u1 = *reinterpret_cast<const float4*>(&w1s[k][64 + tx * 4]);
            float4 v0 = *reinterpret_cast<const float4*>(&w3s[k][tx * 4]);
            float4 v1 = *reinterpret_cast<const float4*>(&w3s[k][64 + tx * 4]);
            float av[8] = {a0.x, a0.y, a0.z, a0.w, a1.x, a1.y, a1.z, a1.w};
            float uv[8] = {u0.x, u0.y, u0.z, u0.w, u1.x, u1.y, u1.z, u1.w};
            float vv[8] = {v0.x, v0.y, v0.z, v0.w, v1.x, v1.y, v1.z, v1.w};
#pragma unroll
            for (int i = 0; i < 8; ++i)
#pragma unroll
                for (int j = 0; j < 8; ++j) {
                    acch[i][j] = fmaf(av[i], uv[j], acch[i][j]);
                    accg[i][j] = fmaf(av[i], vv[j], accg[i][j]);
                }
        }
        __syncthreads();
    }

    // epilogue: a = silu(h) * g
#pragma unroll
    for (int i = 0; i < 8; ++i) {
        int m = (i < 4) ? (ty * 4 + i) : (64 + ty * 4 + (i - 4));
        int p = ps[m];
        if (p < 0) continue;
        float* dst = a_buf + (size_t)p * H_ + n0;
        float4 o0, o1;
        o0.x = silu_f(acch[i][0]) * accg[i][0];
        o0.y = silu_f(acch[i][1]) * accg[i][1];
        o0.z = silu_f(acch[i][2]) * accg[i][2];
        o0.w = silu_f(acch[i][3]) * accg[i][3];
        o1.x = silu_f(acch[i][4]) * accg[i][4];
        o1.y = silu_f(acch[i][5]) * accg[i][5];
        o1.z = silu_f(acch[i][6]) * accg[i][6];
        o1.w = silu_f(acch[i][7]) * accg[i][7];
        *reinterpret_cast<float4*>(dst + tx * 4)      = o0;
        *reinterpret_cast<float4*>(dst + 64 + tx * 4) = o1;
    }
}

// ================= GEMM2: out[t] += wt * (a[p] @ w2[e]) =================
__global__ __launch_bounds__(256) void gemm2_kernel(
    const float* __restrict__ a_buf, const float* __restrict__ w2,
    const int* __restrict__ cnt, const int* __restrict__ list_p,
    const float* __restrict__ list_w, float* __restrict__ out)
{
    const int bid = blockIdx.x;
    const int e   = bid / (MT_TILES * NT2);
    const int rem = bid % (MT_TILES * NT2);
    const int mt  = rem / NT2;
    const int nt  = rem % NT2;
    const int ne  = cnt[e];
    if (mt * BM >= ne) return;
    const int n0  = nt * BN;
    const int tid = threadIdx.x;

    __shared__ int   ps[BM];
    __shared__ float wts[BM];
    __shared__ float as[BK][BM + 4];
    __shared__ float w2s[BK][BN + 4];

    if (tid < BM) {
        int slot = mt * BM + tid;
        if (slot < ne) {
            ps[tid]  = list_p[(size_t)e * T_ + slot];
            wts[tid] = list_w[(size_t)e * T_ + slot];
        } else { ps[tid] = -1; wts[tid] = 0.f; }
    }
    __syncthreads();

    float acc[8][8];
#pragma unroll
    for (int i = 0; i < 8; ++i)
#pragma unroll
        for (int j = 0; j < 8; ++j) acc[i][j] = 0.f;

    const int ty = tid >> 4, tx = tid & 15;
    const int mrow = tid >> 1, mq = tid & 1;
    const int wkk = tid >> 4,  wc4 = tid & 15;
    int arow = ps[mrow]; if (arow < 0) arow = 0;   // safe row (p=0 always written)

    for (int k0 = 0; k0 < H_; k0 += BK) {
        const float4* asrc = reinterpret_cast<const float4*>(a_buf + (size_t)arow * H_ + k0 + mq * 8);
        float4 xv0 = asrc[0];
        float4 xv1 = asrc[1];
        const float* b2p = w2 + ((size_t)e * H_ + k0 + wkk) * D_ + n0;
        float4 bA = *reinterpret_cast<const float4*>(b2p + wc4 * 4);
        float4 bB = *reinterpret_cast<const float4*>(b2p + wc4 * 4 + 64);

        as[mq * 8 + 0][mrow] = xv0.x; as[mq * 8 + 1][mrow] = xv0.y;
        as[mq * 8 + 2][mrow] = xv0.z; as[mq * 8 + 3][mrow] = xv0.w;
        as[mq * 8 + 4][mrow] = xv1.x; as[mq * 8 + 5][mrow] = xv1.y;
        as[mq * 8 + 6][mrow] = xv1.z; as[mq * 8 + 7][mrow] = xv1.w;
        *reinterpret_cast<float4*>(&w2s[wkk][wc4 * 4])      = bA;
        *reinterpret_cast<float4*>(&w2s[wkk][wc4 * 4 + 64]) = bB;
        __syncthreads();

#pragma unroll
        for (int k = 0; k < BK; ++k) {
            float4 a0 = *reinterpret_cast<const float4*>(&as[k][ty * 4]);
            float4 a1 = *reinterpret_cast<const float4*>(&as[k][64 + ty * 4]);
            float4 u0 = *reinterpret_cast<const float4*>(&w2s[k][tx * 4]);
            float4 u1 = *reinterpret_cast<const float4*>(&w2s[k][64 + tx * 4]);
            float av[8] = {a0.x, a0.y, a0.z, a0.w, a1.x, a1.y, a1.z, a1.w};
            float uv[8] = {u0.x, u0.y, u0.z, u0.w, u1.x, u1.y, u1.z, u1.w};
#pragma unroll
            for (int i = 0; i < 8; ++i)
#pragma unroll
                for (int j = 0; j < 8; ++j)
                    acc[i][j] = fmaf(av[i], uv[j], acc[i][j]);
        }
        __syncthreads();
    }

    // epilogue: out[t, n0+c] += wt * acc   (4 contributions per element total)
#pragma unroll
    for (int i = 0; i < 8; ++i) {
        int m = (i < 4) ? (ty * 4 + i) : (64 + ty * 4 + (i - 4));
        int p = ps[m];
        if (p < 0) continue;
        int t = p >> 2;
        float wt = wts[m];
        float* dst = out + (size_t)t * D_ + n0;
#pragma unroll
        for (int j = 0; j < 4; ++j) atomicAdd(dst + tx * 4 + j,      wt * acc[i][j]);
#pragma unroll
        for (int j = 0; j < 4; ++j) atomicAdd(dst + 64 + tx * 4 + j, wt * acc[i][j + 4]);
    }
}

// ================= lb_loss =================
__global__ __launch_bounds__(256) void lb_kernel(
    const float* __restrict__ nsc, const int* __restrict__ cnt, float* __restrict__ out)
{
    const int tid = threadIdx.x;
    float part[E_];
#pragma unroll
    for (int e = 0; e < E_; ++e) part[e] = 0.f;
    for (int t = tid; t < T_; t += 256) {
        const float4* r4 = reinterpret_cast<const float4*>(nsc + (size_t)t * E_);
#pragma unroll
        for (int q = 0; q < 4; ++q) {
            float4 v = r4[q];
            part[q * 4 + 0] += v.x; part[q * 4 + 1] += v.y;
            part[q * 4 + 2] += v.z; part[q * 4 + 3] += v.w;
        }
    }
#pragma unroll
    for (int e = 0; e < E_; ++e) {
        float v = part[e];
#pragma unroll
        for (int off = 32; off > 0; off >>= 1) v += __shfl_down(v, off);
        part[e] = v;
    }
    __shared__ float red[4 * E_];
    const int wave = tid >> 6, lane = tid & 63;
    if (lane == 0) {
#pragma unroll
        for (int e = 0; e < E_; ++e) red[wave * E_ + e] = part[e];
    }
    __syncthreads();
    if (tid == 0) {
        float lb = 0.f;
        for (int e = 0; e < E_; ++e) {
            float s = red[0 * E_ + e] + red[1 * E_ + e] + red[2 * E_ + e] + red[3 * E_ + e];
            lb += ((float)cnt[e] / (float)T_) * (s / (float)T_);
        }
        out[(size_t)T_ * D_] = (float)E_ * lb;
    }
}

// ================= launch =================
extern "C" void kernel_launch(void* const* d_in, const int* in_sizes, int n_in,
                              void* d_out, int out_size, void* d_ws, size_t ws_size,
                              hipStream_t stream)
{
    const float* x    = (const float*)d_in[0];
    const float* gw   = (const float*)d_in[1];
    const float* bias = (const float*)d_in[2];
    const float* w1   = (const float*)d_in[3];
    const float* w3   = (const float*)d_in[4];
    const float* w2   = (const float*)d_in[5];
    float* out = (float*)d_out;
    char*  ws  = (char*)d_ws;

    int*   cnt    = (int*)  (ws + WS_CNT);
    int*   list_p = (int*)  (ws + WS_LISTP);
    float* list_w = (float*)(ws + WS_LISTW);
    float* nsc    = (float*)(ws + WS_NSC);
    float* a_buf  = (float*)(ws + WS_ABUF);

    // d_out / d_ws are re-poisoned before every timed call: zero what we accumulate into
    hipMemsetAsync(d_out, 0, (size_t)out_size * sizeof(float), stream);
    hipMemsetAsync(ws, 0, 256, stream);   // cnt

    router_kernel<<<T_, 256, 0, stream>>>(x, gw, bias, cnt, nsc, list_p, list_w);
    gemm1_kernel<<<E_ * MT_TILES * NT1, 256, 0, stream>>>(x, w1, w3, cnt, list_p, a_buf);
    gemm2_kernel<<<E_ * MT_TILES * NT2, 256, 0, stream>>>(a_buf, w2, cnt, list_p, list_w, out);
    lb_kernel<<<1, 256, 0, stream>>>(nsc, cnt, out);
}

// Round 4
// 659.995 us; speedup vs baseline: 1.8211x; 1.8211x over previous
//
#include <hip/hip_runtime.h>
#include <math.h>

// ---------------- problem constants ----------------
constexpr int T_ = 2048;   // tokens (B*S)
constexpr int D_ = 1024;   // model dim
constexpr int E_ = 16;     // experts
constexpr int H_ = 1024;   // expert hidden
constexpr int K_ = 4;      // top-k
constexpr float EPS_ = 1e-6f;

// ---------------- GEMM tiling (MFMA) ----------------
constexpr int BM = 128, BN = 128, BK = 32;
constexpr int MT_TILES = T_ / BM;   // 16 (worst case: all tokens to one expert)
constexpr int NT1 = H_ / BN;        // 8
constexpr int NT2 = D_ / BN;        // 8

// ---------------- workspace layout (bytes) ----------------
constexpr size_t WS_CNT   = 0;                                  // E ints
constexpr size_t WS_LISTP = 256;                                // E*T ints
constexpr size_t WS_LISTW = WS_LISTP + (size_t)E_ * T_ * 4;     // E*T floats
constexpr size_t WS_NSC   = WS_LISTW + (size_t)E_ * T_ * 4;     // T*E floats
constexpr size_t WS_AHI   = WS_NSC  + (size_t)T_ * E_ * 4;      // T*K*H bf16 hi
constexpr size_t WS_ALO   = WS_AHI  + (size_t)T_ * K_ * H_ * 2; // T*K*H bf16 lo
// total ~34 MB

using short8  = __attribute__((ext_vector_type(8))) short;
using floatx4 = __attribute__((ext_vector_type(4))) float;

#define MFMA16(a, b, c) __builtin_amdgcn_mfma_f32_16x16x32_bf16((a), (b), (c), 0, 0, 0)

__device__ __forceinline__ float silu_f(float h) {
    return h / (1.f + expf(-h));
}

// split fp32 -> bf16 hi (truncate) + bf16 lo (truncated residual).
// hi + lo carries ~14 mantissa bits; MFMA 3-product emulation keeps error ~2^-14.
__device__ __forceinline__ void pack_split8(const float f[8], unsigned short* dh, unsigned short* dl) {
    unsigned hb[8], lb[8];
#pragma unroll
    for (int i = 0; i < 8; ++i) {
        unsigned b = __float_as_uint(f[i]);
        float hf = __uint_as_float(b & 0xFFFF0000u);
        float r = f[i] - hf;
        hb[i] = b >> 16;
        lb[i] = __float_as_uint(r) >> 16;
    }
    uint4 hv, lv;
    hv.x = hb[0] | (hb[1] << 16); hv.y = hb[2] | (hb[3] << 16);
    hv.z = hb[4] | (hb[5] << 16); hv.w = hb[6] | (hb[7] << 16);
    lv.x = lb[0] | (lb[1] << 16); lv.y = lb[2] | (lb[3] << 16);
    lv.z = lb[4] | (lb[5] << 16); lv.w = lb[6] | (lb[7] << 16);
    *reinterpret_cast<uint4*>(dh) = hv;
    *reinterpret_cast<uint4*>(dl) = lv;
}

// stage 8 consecutive fp32 (k-run) from a contiguous row
__device__ __forceinline__ void stage_row8(const float* src, unsigned short* dh, unsigned short* dl) {
    float4 f0 = *reinterpret_cast<const float4*>(src);
    float4 f1 = *reinterpret_cast<const float4*>(src + 4);
    float f[8] = {f0.x, f0.y, f0.z, f0.w, f1.x, f1.y, f1.z, f1.w};
    pack_split8(f, dh, dl);
}

// stage 8 k-strided fp32 from a [K][N] weight (transpose-in-register)
__device__ __forceinline__ void stage_w8(const float* base, int kstart, unsigned short* dh, unsigned short* dl) {
    float f[8];
#pragma unroll
    for (int j = 0; j < 8; ++j) f[j] = base[(size_t)(kstart + j) * H_];
    pack_split8(f, dh, dl);
}

// ================= router (unchanged; fp32 selection) =================
__global__ __launch_bounds__(256) void router_kernel(
    const float* __restrict__ x, const float* __restrict__ gw,
    const float* __restrict__ bias,
    int* __restrict__ cnt, float* __restrict__ nsc,
    int* __restrict__ list_p, float* __restrict__ list_w)
{
    const int t = blockIdx.x;
    const int tid = threadIdx.x;

    float part[E_];
#pragma unroll
    for (int e = 0; e < E_; ++e) part[e] = 0.f;

    const float* xr = x + (size_t)t * D_;
    for (int it = 0; it < D_ / 256; ++it) {
        int d = it * 256 + tid;
        float xv = xr[d];
        const float4* g4 = reinterpret_cast<const float4*>(gw + (size_t)d * E_);
#pragma unroll
        for (int q = 0; q < 4; ++q) {
            float4 gv = g4[q];
            part[q * 4 + 0] += xv * gv.x;
            part[q * 4 + 1] += xv * gv.y;
            part[q * 4 + 2] += xv * gv.z;
            part[q * 4 + 3] += xv * gv.w;
        }
    }
#pragma unroll
    for (int e = 0; e < E_; ++e) {
        float v = part[e];
#pragma unroll
        for (int off = 32; off > 0; off >>= 1) v += __shfl_down(v, off);
        part[e] = v;
    }
    __shared__ float red[4 * E_];
    const int wave = tid >> 6, lane = tid & 63;
    if (lane == 0) {
#pragma unroll
        for (int e = 0; e < E_; ++e) red[wave * E_ + e] = part[e];
    }
    __syncthreads();

    __shared__ float sc[E_];
    if (tid < E_) {
        float s = red[0 * E_ + tid] + red[1 * E_ + tid] + red[2 * E_ + tid] + red[3 * E_ + tid];
        s += bias[tid];
        sc[tid] = 1.f / (1.f + expf(-s));
    }
    __syncthreads();

    if (tid == 0) {
        float sum = 0.f;
#pragma unroll
        for (int e = 0; e < E_; ++e) sum += sc[e];
        float den = sum + EPS_;
        float ns[E_];
#pragma unroll
        for (int e = 0; e < E_; ++e) {
            ns[e] = sc[e] / den;
            nsc[(size_t)t * E_ + e] = ns[e];
        }
        bool used[E_];
#pragma unroll
        for (int e = 0; e < E_; ++e) used[e] = false;
        int sel[K_]; float selw[K_]; float wsum = 0.f;
        for (int k = 0; k < K_; ++k) {
            float best = -1.f; int bi = 0;
            for (int e = 0; e < E_; ++e)
                if (!used[e] && ns[e] > best) { best = ns[e]; bi = e; }
            used[bi] = true; sel[k] = bi; selw[k] = best; wsum += best;
        }
        float wden = wsum + EPS_;
        for (int k = 0; k < K_; ++k) {
            int e = sel[k];
            int slot = atomicAdd(&cnt[e], 1);
            list_p[(size_t)e * T_ + slot] = t * K_ + k;
            list_w[(size_t)e * T_ + slot] = selw[k] / wden;
        }
    }
}

// ================= GEMM1 (MFMA): a = silu(x@w1)*(x@w3), split-bf16 =================
// LDS fragment order: run index (f, kc, r16) -> [(f*4+kc)*16 + r16] * 8 bf16.
// Wave reads frag f at base + f*512 + lane*8 -> lane-linear, conflict-free.
__global__ __launch_bounds__(256, 2) void gemm1_mfma(
    const float* __restrict__ x, const float* __restrict__ w1,
    const float* __restrict__ w3, const int* __restrict__ cnt,
    const int* __restrict__ list_p,
    unsigned short* __restrict__ a_hi, unsigned short* __restrict__ a_lo)
{
    const int bid = blockIdx.x;
    const int e   = bid / (MT_TILES * NT1);
    const int rem = bid % (MT_TILES * NT1);
    const int mt  = rem / NT1;
    const int nt  = rem % NT1;
    const int ne  = cnt[e];
    if (mt * BM >= ne) return;
    const int n0  = nt * BN;
    const int tid = threadIdx.x;

    __shared__ int ps[BM];
    __shared__ int ts[BM];
    __shared__ alignas(16) unsigned short Ah[4096], Al[4096];
    __shared__ alignas(16) unsigned short B1h[4096], B1l[4096], B3h[4096], B3l[4096];

    if (tid < BM) {
        int slot = mt * BM + tid;
        if (slot < ne) { int p = list_p[(size_t)e * T_ + slot]; ps[tid] = p; ts[tid] = p >> 2; }
        else           { ps[tid] = -1; ts[tid] = 0; }
    }
    __syncthreads();

    // A tasks: q = tid, tid+256; decode mf=q>>6, kc=(q>>4)&3, row=q&15 (run==q)
    const int qa1 = tid + 256;
    const float* ap0 = x + (size_t)ts[(tid >> 6) * 16 + (tid & 15)] * D_ + ((tid >> 4) & 3) * 8;
    const float* ap1 = x + (size_t)ts[(qa1 >> 6) * 16 + (qa1 & 15)] * D_ + ((qa1 >> 4) & 3) * 8;
    const int offA0 = tid * 8, offA1 = qa1 * 8;

    // B tasks: kc = tid>>7 and +2; nf=(tid>>4)&7, col=tid&15 (same base both tasks)
    const int bnf = (tid >> 4) & 7, bcol = tid & 15;
    const int kcb = tid >> 7;                    // 0 or 1; second task kcb+2
    const size_t wbase = (size_t)e * D_ * H_ + n0 + bnf * 16 + bcol;
    const float* b1p = w1 + wbase;
    const float* b3p = w3 + wbase;
    const int offB0 = (bnf * 64 + kcb * 16 + bcol) * 8;
    const int offB1 = offB0 + 256;               // kc+2 -> +2*16*8

    const int w  = tid >> 6, l = tid & 63;
    const int wr = w >> 1, wc = w & 1;           // wave tile 64x64
    const int lo8 = l * 8;

    floatx4 acch[4][4], accg[4][4];
#pragma unroll
    for (int i = 0; i < 4; ++i)
#pragma unroll
        for (int j = 0; j < 4; ++j) { acch[i][j] = (floatx4)0.f; accg[i][j] = (floatx4)0.f; }

    for (int k0 = 0; k0 < D_; k0 += BK) {
        stage_row8(ap0 + k0, Ah + offA0, Al + offA0);
        stage_row8(ap1 + k0, Ah + offA1, Al + offA1);
        stage_w8(b1p, k0 + kcb * 8,       B1h + offB0, B1l + offB0);
        stage_w8(b1p, k0 + (kcb + 2) * 8, B1h + offB1, B1l + offB1);
        stage_w8(b3p, k0 + kcb * 8,       B3h + offB0, B3l + offB0);
        stage_w8(b3p, k0 + (kcb + 2) * 8, B3h + offB1, B3l + offB1);
        __syncthreads();

        short8 ah[4], al[4];
#pragma unroll
        for (int mi = 0; mi < 4; ++mi) {
            int base = (wr * 4 + mi) * 512 + lo8;
            ah[mi] = *reinterpret_cast<const short8*>(Ah + base);
            al[mi] = *reinterpret_cast<const short8*>(Al + base);
        }
#pragma unroll
        for (int nj = 0; nj < 4; ++nj) {
            int bb = (wc * 4 + nj) * 512 + lo8;
            short8 b1hv = *reinterpret_cast<const short8*>(B1h + bb);
            short8 b1lv = *reinterpret_cast<const short8*>(B1l + bb);
            short8 b3hv = *reinterpret_cast<const short8*>(B3h + bb);
            short8 b3lv = *reinterpret_cast<const short8*>(B3l + bb);
#pragma unroll
            for (int mi = 0; mi < 4; ++mi) {
                acch[mi][nj] = MFMA16(ah[mi], b1hv, acch[mi][nj]);
                acch[mi][nj] = MFMA16(al[mi], b1hv, acch[mi][nj]);
                acch[mi][nj] = MFMA16(ah[mi], b1lv, acch[mi][nj]);
                accg[mi][nj] = MFMA16(ah[mi], b3hv, accg[mi][nj]);
                accg[mi][nj] = MFMA16(al[mi], b3hv, accg[mi][nj]);
                accg[mi][nj] = MFMA16(ah[mi], b3lv, accg[mi][nj]);
            }
        }
        __syncthreads();
    }

    // epilogue: a = silu(h)*g, split to bf16 hi/lo. C/D: col=l&15, row=4*(l>>4)+r
    const int g4 = (l >> 4) * 4;
#pragma unroll
    for (int mi = 0; mi < 4; ++mi) {
#pragma unroll
        for (int r = 0; r < 4; ++r) {
            int m = wr * 64 + mi * 16 + g4 + r;
            int p = ps[m];
            if (p < 0) continue;
            size_t rowoff = (size_t)p * H_ + n0 + wc * 64 + (l & 15);
#pragma unroll
            for (int nj = 0; nj < 4; ++nj) {
                float h = acch[mi][nj][r];
                float g = accg[mi][nj][r];
                float a = silu_f(h) * g;
                unsigned b = __float_as_uint(a);
                float rr = a - __uint_as_float(b & 0xFFFF0000u);
                a_hi[rowoff + nj * 16] = (unsigned short)(b >> 16);
                a_lo[rowoff + nj * 16] = (unsigned short)(__float_as_uint(rr) >> 16);
            }
        }
    }
}

// ================= GEMM2 (MFMA): out[t] += wt * (a[p] @ w2[e]) =================
__global__ __launch_bounds__(256, 2) void gemm2_mfma(
    const unsigned short* __restrict__ a_hi, const unsigned short* __restrict__ a_lo,
    const float* __restrict__ w2, const int* __restrict__ cnt,
    const int* __restrict__ list_p, const float* __restrict__ list_w,
    float* __restrict__ out)
{
    const int bid = blockIdx.x;
    const int e   = bid / (MT_TILES * NT2);
    const int rem = bid % (MT_TILES * NT2);
    const int mt  = rem / NT2;
    const int nt  = rem % NT2;
    const int ne  = cnt[e];
    if (mt * BM >= ne) return;
    const int n0  = nt * BN;
    const int tid = threadIdx.x;

    __shared__ int   ps[BM];
    __shared__ float wts[BM];
    __shared__ int   ats[BM];
    __shared__ alignas(16) unsigned short Ahs[4096], Als[4096], Bh[4096], Bl[4096];

    if (tid < BM) {
        int slot = mt * BM + tid;
        if (slot < ne) {
            int p = list_p[(size_t)e * T_ + slot];
            ps[tid] = p; ats[tid] = p; wts[tid] = list_w[(size_t)e * T_ + slot];
        } else { ps[tid] = -1; ats[tid] = 0; wts[tid] = 0.f; }
    }
    __syncthreads();

    const int qa1 = tid + 256;
    const size_t ar0 = (size_t)ats[(tid >> 6) * 16 + (tid & 15)] * H_ + ((tid >> 4) & 3) * 8;
    const size_t ar1 = (size_t)ats[(qa1 >> 6) * 16 + (qa1 & 15)] * H_ + ((qa1 >> 4) & 3) * 8;
    const int offA0 = tid * 8, offA1 = qa1 * 8;

    const int bnf = (tid >> 4) & 7, bcol = tid & 15;
    const int kcb = tid >> 7;
    const float* b2p = w2 + (size_t)e * H_ * D_ + n0 + bnf * 16 + bcol;
    const int offB0 = (bnf * 64 + kcb * 16 + bcol) * 8;
    const int offB1 = offB0 + 256;

    const int w  = tid >> 6, l = tid & 63;
    const int wr = w >> 1, wc = w & 1;
    const int lo8 = l * 8;

    floatx4 acc[4][4];
#pragma unroll
    for (int i = 0; i < 4; ++i)
#pragma unroll
        for (int j = 0; j < 4; ++j) acc[i][j] = (floatx4)0.f;

    for (int k0 = 0; k0 < H_; k0 += BK) {
        // A: pre-split bf16, direct 16B copies
        *reinterpret_cast<uint4*>(Ahs + offA0) = *reinterpret_cast<const uint4*>(a_hi + ar0 + k0);
        *reinterpret_cast<uint4*>(Als + offA0) = *reinterpret_cast<const uint4*>(a_lo + ar0 + k0);
        *reinterpret_cast<uint4*>(Ahs + offA1) = *reinterpret_cast<const uint4*>(a_hi + ar1 + k0);
        *reinterpret_cast<uint4*>(Als + offA1) = *reinterpret_cast<const uint4*>(a_lo + ar1 + k0);
        // B: fp32 w2, split + transpose in regs
        stage_w8(b2p, k0 + kcb * 8,       Bh + offB0, Bl + offB0);
        stage_w8(b2p, k0 + (kcb + 2) * 8, Bh + offB1, Bl + offB1);
        __syncthreads();

        short8 ah[4], al[4];
#pragma unroll
        for (int mi = 0; mi < 4; ++mi) {
            int base = (wr * 4 + mi) * 512 + lo8;
            ah[mi] = *reinterpret_cast<const short8*>(Ahs + base);
            al[mi] = *reinterpret_cast<const short8*>(Als + base);
        }
#pragma unroll
        for (int nj = 0; nj < 4; ++nj) {
            int bb = (wc * 4 + nj) * 512 + lo8;
            short8 bhv = *reinterpret_cast<const short8*>(Bh + bb);
            short8 blv = *reinterpret_cast<const short8*>(Bl + bb);
#pragma unroll
            for (int mi = 0; mi < 4; ++mi) {
                acc[mi][nj] = MFMA16(ah[mi], bhv, acc[mi][nj]);
                acc[mi][nj] = MFMA16(al[mi], bhv, acc[mi][nj]);
                acc[mi][nj] = MFMA16(ah[mi], blv, acc[mi][nj]);
            }
        }
        __syncthreads();
    }

    const int g4 = (l >> 4) * 4;
#pragma unroll
    for (int mi = 0; mi < 4; ++mi) {
#pragma unroll
        for (int r = 0; r < 4; ++r) {
            int m = wr * 64 + mi * 16 + g4 + r;
            int p = ps[m];
            if (p < 0) continue;
            int t = p >> 2;
            float wt = wts[m];
            float* dst = out + (size_t)t * D_ + n0 + wc * 64 + (l & 15);
#pragma unroll
            for (int nj = 0; nj < 4; ++nj)
                atomicAdd(dst + nj * 16, wt * acc[mi][nj][r]);
        }
    }
}

// ================= lb_loss =================
__global__ __launch_bounds__(256) void lb_kernel(
    const float* __restrict__ nsc, const int* __restrict__ cnt, float* __restrict__ out)
{
    const int tid = threadIdx.x;
    float part[E_];
#pragma unroll
    for (int e = 0; e < E_; ++e) part[e] = 0.f;
    for (int t = tid; t < T_; t += 256) {
        const float4* r4 = reinterpret_cast<const float4*>(nsc + (size_t)t * E_);
#pragma unroll
        for (int q = 0; q < 4; ++q) {
            float4 v = r4[q];
            part[q * 4 + 0] += v.x; part[q * 4 + 1] += v.y;
            part[q * 4 + 2] += v.z; part[q * 4 + 3] += v.w;
        }
    }
#pragma unroll
    for (int e = 0; e < E_; ++e) {
        float v = part[e];
#pragma unroll
        for (int off = 32; off > 0; off >>= 1) v += __shfl_down(v, off);
        part[e] = v;
    }
    __shared__ float red[4 * E_];
    const int wave = tid >> 6, lane = tid & 63;
    if (lane == 0) {
#pragma unroll
        for (int e = 0; e < E_; ++e) red[wave * E_ + e] = part[e];
    }
    __syncthreads();
    if (tid == 0) {
        float lb = 0.f;
        for (int e = 0; e < E_; ++e) {
            float s = red[0 * E_ + e] + red[1 * E_ + e] + red[2 * E_ + e] + red[3 * E_ + e];
            lb += ((float)cnt[e] / (float)T_) * (s / (float)T_);
        }
        out[(size_t)T_ * D_] = (float)E_ * lb;
    }
}

// ================= launch =================
extern "C" void kernel_launch(void* const* d_in, const int* in_sizes, int n_in,
                              void* d_out, int out_size, void* d_ws, size_t ws_size,
                              hipStream_t stream)
{
    const float* x    = (const float*)d_in[0];
    const float* gw   = (const float*)d_in[1];
    const float* bias = (const float*)d_in[2];
    const float* w1   = (const float*)d_in[3];
    const float* w3   = (const float*)d_in[4];
    const float* w2   = (const float*)d_in[5];
    float* out = (float*)d_out;
    char*  ws  = (char*)d_ws;

    int*   cnt    = (int*)  (ws + WS_CNT);
    int*   list_p = (int*)  (ws + WS_LISTP);
    float* list_w = (float*)(ws + WS_LISTW);
    float* nsc    = (float*)(ws + WS_NSC);
    unsigned short* a_hi = (unsigned short*)(ws + WS_AHI);
    unsigned short* a_lo = (unsigned short*)(ws + WS_ALO);

    hipMemsetAsync(d_out, 0, (size_t)out_size * sizeof(float), stream);
    hipMemsetAsync(ws, 0, 256, stream);   // cnt

    router_kernel<<<T_, 256, 0, stream>>>(x, gw, bias, cnt, nsc, list_p, list_w);
    gemm1_mfma<<<E_ * MT_TILES * NT1, 256, 0, stream>>>(x, w1, w3, cnt, list_p, a_hi, a_lo);
    gemm2_mfma<<<E_ * MT_TILES * NT2, 256, 0, stream>>>(a_hi, a_lo, w2, cnt, list_p, list_w, out);
    lb_kernel<<<1, 256, 0, stream>>>(nsc, cnt, out);
}

// Round 5
// 592.720 us; speedup vs baseline: 2.0278x; 1.1135x over previous
//
#include <hip/hip_runtime.h>
#include <math.h>

// ---------------- problem constants ----------------
constexpr int T_ = 2048;   // tokens (B*S)
constexpr int D_ = 1024;   // model dim
constexpr int E_ = 16;     // experts
constexpr int H_ = 1024;   // expert hidden
constexpr int K_ = 4;      // top-k
constexpr float EPS_ = 1e-6f;

// ---------------- fast-path tiling: BM=128, BN=64, BK=32, 256 thr ----------------
constexpr int FMT = 16;      // worst-case M-tiles (T*K rows / 128 if all on one expert)
constexpr int FNT = 16;      // N-tiles of 64 over 1024

// ---------------- fallback (round-4) tiling ----------------
constexpr int BM = 128, BN = 128, BK = 32;
constexpr int MT_TILES = T_ / BM;   // 16
constexpr int NT1 = H_ / BN;        // 8
constexpr int NT2 = D_ / BN;        // 8

// ---------------- fast-path workspace layout (bytes) ----------------
constexpr size_t FWS_CNT   = 0;                                   // E ints
constexpr size_t FWS_LISTP = 256;
constexpr size_t FWS_LISTW = FWS_LISTP + (size_t)E_ * T_ * 4;
constexpr size_t FWS_NSC   = FWS_LISTW + (size_t)E_ * T_ * 4;
constexpr size_t FWS_XHI   = FWS_NSC  + (size_t)T_ * E_ * 4;      // T*D shorts
constexpr size_t FWS_XLO   = FWS_XHI  + (size_t)T_ * D_ * 2;
constexpr size_t FWS_AHI   = FWS_XLO  + (size_t)T_ * D_ * 2;      // T*K*H shorts
constexpr size_t FWS_ALO   = FWS_AHI  + (size_t)T_ * K_ * H_ * 2;
constexpr size_t FWS_W1S   = FWS_ALO  + (size_t)T_ * K_ * H_ * 2; // swizzled hi/lo, 64 MB
constexpr size_t FWS_W3S   = FWS_W1S  + (size_t)E_ * D_ * H_ * 4;
constexpr size_t FWS_W2S   = FWS_W3S  + (size_t)E_ * D_ * H_ * 4;
constexpr size_t FWS_NEED  = FWS_W2S  + (size_t)E_ * H_ * D_ * 4; // ~232 MB

// ---------------- fallback workspace layout ----------------
constexpr size_t WS_CNT   = 0;
constexpr size_t WS_LISTP = 256;
constexpr size_t WS_LISTW = WS_LISTP + (size_t)E_ * T_ * 4;
constexpr size_t WS_NSC   = WS_LISTW + (size_t)E_ * T_ * 4;
constexpr size_t WS_AHI   = WS_NSC  + (size_t)T_ * E_ * 4;
constexpr size_t WS_ALO   = WS_AHI  + (size_t)T_ * K_ * H_ * 2;

using short8  = __attribute__((ext_vector_type(8))) short;
using floatx4 = __attribute__((ext_vector_type(4))) float;

#define MFMA16(a, b, c) __builtin_amdgcn_mfma_f32_16x16x32_bf16((a), (b), (c), 0, 0, 0)

__device__ __forceinline__ float silu_f(float h) {
    return h / (1.f + expf(-h));
}

// async 16B global->LDS (per-lane global src; LDS dest = wave base + lane*16)
__device__ __forceinline__ void gll16(const void* g, void* l) {
    __builtin_amdgcn_global_load_lds(
        (const __attribute__((address_space(1))) unsigned int*)g,
        (__attribute__((address_space(3))) unsigned int*)l, 16, 0, 0);
}

// split fp32 -> bf16 hi (truncate) + bf16 lo (truncated residual)
__device__ __forceinline__ void pack_split8(const float f[8], unsigned short* dh, unsigned short* dl) {
    unsigned hb[8], lb[8];
#pragma unroll
    for (int i = 0; i < 8; ++i) {
        unsigned b = __float_as_uint(f[i]);
        float hf = __uint_as_float(b & 0xFFFF0000u);
        float r = f[i] - hf;
        hb[i] = b >> 16;
        lb[i] = __float_as_uint(r) >> 16;
    }
    uint4 hv, lv;
    hv.x = hb[0] | (hb[1] << 16); hv.y = hb[2] | (hb[3] << 16);
    hv.z = hb[4] | (hb[5] << 16); hv.w = hb[6] | (hb[7] << 16);
    lv.x = lb[0] | (lb[1] << 16); lv.y = lb[2] | (lb[3] << 16);
    lv.z = lb[4] | (lb[5] << 16); lv.w = lb[6] | (lb[7] << 16);
    *reinterpret_cast<uint4*>(dh) = hv;
    *reinterpret_cast<uint4*>(dl) = lv;
}

__device__ __forceinline__ void stage_row8(const float* src, unsigned short* dh, unsigned short* dl) {
    float4 f0 = *reinterpret_cast<const float4*>(src);
    float4 f1 = *reinterpret_cast<const float4*>(src + 4);
    float f[8] = {f0.x, f0.y, f0.z, f0.w, f1.x, f1.y, f1.z, f1.w};
    pack_split8(f, dh, dl);
}

__device__ __forceinline__ void stage_w8(const float* base, int kstart, unsigned short* dh, unsigned short* dl) {
    float f[8];
#pragma unroll
    for (int j = 0; j < 8; ++j) f[j] = base[(size_t)(kstart + j) * H_];
    pack_split8(f, dh, dl);
}

// ================= router =================
__global__ __launch_bounds__(256) void router_kernel(
    const float* __restrict__ x, const float* __restrict__ gw,
    const float* __restrict__ bias,
    int* __restrict__ cnt, float* __restrict__ nsc,
    int* __restrict__ list_p, float* __restrict__ list_w)
{
    const int t = blockIdx.x;
    const int tid = threadIdx.x;

    float part[E_];
#pragma unroll
    for (int e = 0; e < E_; ++e) part[e] = 0.f;

    const float* xr = x + (size_t)t * D_;
    for (int it = 0; it < D_ / 256; ++it) {
        int d = it * 256 + tid;
        float xv = xr[d];
        const float4* g4 = reinterpret_cast<const float4*>(gw + (size_t)d * E_);
#pragma unroll
        for (int q = 0; q < 4; ++q) {
            float4 gv = g4[q];
            part[q * 4 + 0] += xv * gv.x;
            part[q * 4 + 1] += xv * gv.y;
            part[q * 4 + 2] += xv * gv.z;
            part[q * 4 + 3] += xv * gv.w;
        }
    }
#pragma unroll
    for (int e = 0; e < E_; ++e) {
        float v = part[e];
#pragma unroll
        for (int off = 32; off > 0; off >>= 1) v += __shfl_down(v, off);
        part[e] = v;
    }
    __shared__ float red[4 * E_];
    const int wave = tid >> 6, lane = tid & 63;
    if (lane == 0) {
#pragma unroll
        for (int e = 0; e < E_; ++e) red[wave * E_ + e] = part[e];
    }
    __syncthreads();

    __shared__ float sc[E_];
    if (tid < E_) {
        float s = red[0 * E_ + tid] + red[1 * E_ + tid] + red[2 * E_ + tid] + red[3 * E_ + tid];
        s += bias[tid];
        sc[tid] = 1.f / (1.f + expf(-s));
    }
    __syncthreads();

    if (tid == 0) {
        float sum = 0.f;
#pragma unroll
        for (int e = 0; e < E_; ++e) sum += sc[e];
        float den = sum + EPS_;
        float ns[E_];
#pragma unroll
        for (int e = 0; e < E_; ++e) {
            ns[e] = sc[e] / den;
            nsc[(size_t)t * E_ + e] = ns[e];
        }
        bool used[E_];
#pragma unroll
        for (int e = 0; e < E_; ++e) used[e] = false;
        int sel[K_]; float selw[K_]; float wsum = 0.f;
        for (int k = 0; k < K_; ++k) {
            float best = -1.f; int bi = 0;
            for (int e = 0; e < E_; ++e)
                if (!used[e] && ns[e] > best) { best = ns[e]; bi = e; }
            used[bi] = true; sel[k] = bi; selw[k] = best; wsum += best;
        }
        float wden = wsum + EPS_;
        for (int k = 0; k < K_; ++k) {
            int e = sel[k];
            int slot = atomicAdd(&cnt[e], 1);
            list_p[(size_t)e * T_ + slot] = t * K_ + k;
            list_w[(size_t)e * T_ + slot] = selw[k] / wden;
        }
    }
}

// ================= fast path: weight conversion =================
// Converts w1,w3,w2 fp32 [e][k(1024)][n(1024)] into per-(e,nt,ks) 8KB blocks:
// 2048 shorts hi ++ 2048 shorts lo, fragment-linear: run R=(nf*4+kc)*16+col,
// element j of run R = w[ks*32 + kc*8 + j][nt*64 + nf*16 + col].
__global__ __launch_bounds__(256) void conv_w(
    const float* __restrict__ w1, const float* __restrict__ w3, const float* __restrict__ w2,
    unsigned short* __restrict__ d1, unsigned short* __restrict__ d3, unsigned short* __restrict__ d2)
{
    const int b = blockIdx.x;
    const int wsel = b >> 13;          // 8192 blocks per weight
    const int rem = b & 8191;
    const int e = rem >> 9;
    const int rem2 = rem & 511;
    const int nt = rem2 >> 5;
    const int ks = rem2 & 31;
    const int tid = threadIdx.x;

    const float* src = (wsel == 0 ? w1 : wsel == 1 ? w3 : w2)
                     + ((size_t)e * 1024 + ks * 32) * 1024 + nt * 64;
    unsigned short* dst = (wsel == 0 ? d1 : wsel == 1 ? d3 : d2)
                        + ((size_t)(e * 16 + nt) * 32 + ks) * 4096;

    __shared__ float tile[32][65];
    const int r = tid >> 3, c0 = (tid & 7) * 8;
    float4 v0 = *reinterpret_cast<const float4*>(src + (size_t)r * 1024 + c0);
    float4 v1 = *reinterpret_cast<const float4*>(src + (size_t)r * 1024 + c0 + 4);
    tile[r][c0 + 0] = v0.x; tile[r][c0 + 1] = v0.y; tile[r][c0 + 2] = v0.z; tile[r][c0 + 3] = v0.w;
    tile[r][c0 + 4] = v1.x; tile[r][c0 + 5] = v1.y; tile[r][c0 + 6] = v1.z; tile[r][c0 + 7] = v1.w;
    __syncthreads();

    // run R == tid: nf=tid>>6, kc=(tid>>4)&3, col=tid&15
    const int nf = tid >> 6, kc = (tid >> 4) & 3, col = tid & 15;
    float f[8];
#pragma unroll
    for (int j = 0; j < 8; ++j) f[j] = tile[kc * 8 + j][nf * 16 + col];
    pack_split8(f, dst + tid * 8, dst + 2048 + tid * 8);
}

// x -> hi/lo planes (row-major [t][d] shorts)
__global__ __launch_bounds__(256) void conv_x(
    const float* __restrict__ x, unsigned short* __restrict__ xhi, unsigned short* __restrict__ xlo)
{
    const size_t i = ((size_t)blockIdx.x * 256 + threadIdx.x) * 8;
    float4 a = *reinterpret_cast<const float4*>(x + i);
    float4 b = *reinterpret_cast<const float4*>(x + i + 4);
    float f[8] = {a.x, a.y, a.z, a.w, b.x, b.y, b.z, b.w};
    pack_split8(f, xhi + i, xlo + i);
}

// ================= fast GEMM1: a = silu(x@w1)*(x@w3) =================
// BM=128, BN=64, BK=32; 4 waves; wave tile 64x32; all staging via global_load_lds.
__global__ __launch_bounds__(256, 4) void gemm1_fast(
    const unsigned short* __restrict__ xhi, const unsigned short* __restrict__ xlo,
    const unsigned short* __restrict__ w1s, const unsigned short* __restrict__ w3s,
    const int* __restrict__ cnt, const int* __restrict__ list_p,
    unsigned short* __restrict__ a_hi, unsigned short* __restrict__ a_lo)
{
    const int bid = blockIdx.x;
    const int e   = bid >> 8;
    const int rem = bid & 255;
    const int mt  = rem >> 4;
    const int nt  = rem & 15;
    const int ne  = cnt[e];
    if (mt * 128 >= ne) return;
    const int tid = threadIdx.x;

    __shared__ int ps[128];
    __shared__ int ts[128];
    __shared__ alignas(16) unsigned short Ah[4096], Al[4096];       // 128x32
    __shared__ alignas(16) unsigned short B1h[2048], B1l[2048];     // 32x64
    __shared__ alignas(16) unsigned short B3h[2048], B3l[2048];

    if (tid < 128) {
        int slot = mt * 128 + tid;
        if (slot < ne) { int p = list_p[(size_t)e * T_ + slot]; ps[tid] = p; ts[tid] = p >> 2; }
        else           { ps[tid] = -1; ts[tid] = 0; }
    }
    __syncthreads();

    // A gather tasks: runs tid and tid+256; run R: mf=R>>6, kc=(R>>4)&3, r16=R&15
    const int mf0 = tid >> 6, kc0 = (tid >> 4) & 3, r16 = tid & 15;
    const unsigned short* axh0 = xhi + (size_t)ts[mf0 * 16 + r16] * D_ + kc0 * 8;
    const unsigned short* axl0 = xlo + (size_t)ts[mf0 * 16 + r16] * D_ + kc0 * 8;
    const unsigned short* axh1 = xhi + (size_t)ts[(mf0 + 4) * 16 + r16] * D_ + kc0 * 8;
    const unsigned short* axl1 = xlo + (size_t)ts[(mf0 + 4) * 16 + r16] * D_ + kc0 * 8;

    const unsigned short* b1base = w1s + ((size_t)(e * 16 + nt) * 32) * 4096;
    const unsigned short* b3base = w3s + ((size_t)(e * 16 + nt) * 32) * 4096;

    const int w = tid >> 6, l = tid & 63;
    const int wr = w >> 1, wc = w & 1;
    const int lo8 = l * 8;

    floatx4 acch[4][2], accg[4][2];
#pragma unroll
    for (int i = 0; i < 4; ++i)
#pragma unroll
        for (int j = 0; j < 2; ++j) { acch[i][j] = (floatx4)0.f; accg[i][j] = (floatx4)0.f; }

    for (int k0 = 0; k0 < D_; k0 += 32) {
        const unsigned short* b1 = b1base + (size_t)(k0 >> 5) * 4096;
        const unsigned short* b3 = b3base + (size_t)(k0 >> 5) * 4096;
        gll16(axh0 + k0, Ah + tid * 8);
        gll16(axh1 + k0, Ah + (tid + 256) * 8);
        gll16(axl0 + k0, Al + tid * 8);
        gll16(axl1 + k0, Al + (tid + 256) * 8);
        gll16(b1 + tid * 8,        B1h + tid * 8);
        gll16(b1 + 2048 + tid * 8, B1l + tid * 8);
        gll16(b3 + tid * 8,        B3h + tid * 8);
        gll16(b3 + 2048 + tid * 8, B3l + tid * 8);
        __syncthreads();

        short8 ah[4], al[4];
#pragma unroll
        for (int mi = 0; mi < 4; ++mi) {
            int base = (wr * 4 + mi) * 512 + lo8;
            ah[mi] = *reinterpret_cast<const short8*>(Ah + base);
            al[mi] = *reinterpret_cast<const short8*>(Al + base);
        }
#pragma unroll
        for (int nj = 0; nj < 2; ++nj) {
            int bb = (wc * 2 + nj) * 512 + lo8;
            short8 b1hv = *reinterpret_cast<const short8*>(B1h + bb);
            short8 b1lv = *reinterpret_cast<const short8*>(B1l + bb);
            short8 b3hv = *reinterpret_cast<const short8*>(B3h + bb);
            short8 b3lv = *reinterpret_cast<const short8*>(B3l + bb);
#pragma unroll
            for (int mi = 0; mi < 4; ++mi) {
                acch[mi][nj] = MFMA16(ah[mi], b1hv, acch[mi][nj]);
                acch[mi][nj] = MFMA16(al[mi], b1hv, acch[mi][nj]);
                acch[mi][nj] = MFMA16(ah[mi], b1lv, acch[mi][nj]);
                accg[mi][nj] = MFMA16(ah[mi], b3hv, accg[mi][nj]);
                accg[mi][nj] = MFMA16(al[mi], b3hv, accg[mi][nj]);
                accg[mi][nj] = MFMA16(ah[mi], b3lv, accg[mi][nj]);
            }
        }
        __syncthreads();
    }

    // epilogue: C/D map col=l&15, row=(l>>4)*4+r
    const int g4 = (l >> 4) * 4;
#pragma unroll
    for (int mi = 0; mi < 4; ++mi) {
#pragma unroll
        for (int r = 0; r < 4; ++r) {
            int m = wr * 64 + mi * 16 + g4 + r;
            int p = ps[m];
            if (p < 0) continue;
            size_t ro = (size_t)p * H_ + nt * 64 + wc * 32 + (l & 15);
#pragma unroll
            for (int nj = 0; nj < 2; ++nj) {
                float h = acch[mi][nj][r];
                float g = accg[mi][nj][r];
                float a = silu_f(h) * g;
                unsigned b = __float_as_uint(a);
                float rr = a - __uint_as_float(b & 0xFFFF0000u);
                a_hi[ro + nj * 16] = (unsigned short)(b >> 16);
                a_lo[ro + nj * 16] = (unsigned short)(__float_as_uint(rr) >> 16);
            }
        }
    }
}

// ================= fast GEMM2: out[t] += wt * (a[p] @ w2[e]) =================
__global__ __launch_bounds__(256, 4) void gemm2_fast(
    const unsigned short* __restrict__ a_hi, const unsigned short* __restrict__ a_lo,
    const unsigned short* __restrict__ w2s, const int* __restrict__ cnt,
    const int* __restrict__ list_p, const float* __restrict__ list_w,
    float* __restrict__ out)
{
    const int bid = blockIdx.x;
    const int e   = bid >> 8;
    const int rem = bid & 255;
    const int mt  = rem >> 4;
    const int nt  = rem & 15;
    const int ne  = cnt[e];
    if (mt * 128 >= ne) return;
    const int tid = threadIdx.x;

    __shared__ int   ps[128];
    __shared__ float wts[128];
    __shared__ alignas(16) unsigned short Ah[4096], Al[4096];
    __shared__ alignas(16) unsigned short Bh[2048], Bl[2048];

    if (tid < 128) {
        int slot = mt * 128 + tid;
        if (slot < ne) {
            int p = list_p[(size_t)e * T_ + slot];
            ps[tid] = p; wts[tid] = list_w[(size_t)e * T_ + slot];
        } else { ps[tid] = -1; wts[tid] = 0.f; }
    }
    __syncthreads();

    const int mf0 = tid >> 6, kc0 = (tid >> 4) & 3, r16 = tid & 15;
    int p0 = ps[mf0 * 16 + r16];       if (p0 < 0) p0 = 0;
    int p1 = ps[(mf0 + 4) * 16 + r16]; if (p1 < 0) p1 = 0;
    const unsigned short* aah0 = a_hi + (size_t)p0 * H_ + kc0 * 8;
    const unsigned short* aal0 = a_lo + (size_t)p0 * H_ + kc0 * 8;
    const unsigned short* aah1 = a_hi + (size_t)p1 * H_ + kc0 * 8;
    const unsigned short* aal1 = a_lo + (size_t)p1 * H_ + kc0 * 8;

    const unsigned short* b2base = w2s + ((size_t)(e * 16 + nt) * 32) * 4096;

    const int w = tid >> 6, l = tid & 63;
    const int wr = w >> 1, wc = w & 1;
    const int lo8 = l * 8;

    floatx4 acc[4][2];
#pragma unroll
    for (int i = 0; i < 4; ++i)
#pragma unroll
        for (int j = 0; j < 2; ++j) acc[i][j] = (floatx4)0.f;

    for (int k0 = 0; k0 < H_; k0 += 32) {
        const unsigned short* b2 = b2base + (size_t)(k0 >> 5) * 4096;
        gll16(aah0 + k0, Ah + tid * 8);
        gll16(aah1 + k0, Ah + (tid + 256) * 8);
        gll16(aal0 + k0, Al + tid * 8);
        gll16(aal1 + k0, Al + (tid + 256) * 8);
        gll16(b2 + tid * 8,        Bh + tid * 8);
        gll16(b2 + 2048 + tid * 8, Bl + tid * 8);
        __syncthreads();

        short8 ah[4], al[4];
#pragma unroll
        for (int mi = 0; mi < 4; ++mi) {
            int base = (wr * 4 + mi) * 512 + lo8;
            ah[mi] = *reinterpret_cast<const short8*>(Ah + base);
            al[mi] = *reinterpret_cast<const short8*>(Al + base);
        }
#pragma unroll
        for (int nj = 0; nj < 2; ++nj) {
            int bb = (wc * 2 + nj) * 512 + lo8;
            short8 bhv = *reinterpret_cast<const short8*>(Bh + bb);
            short8 blv = *reinterpret_cast<const short8*>(Bl + bb);
#pragma unroll
            for (int mi = 0; mi < 4; ++mi) {
                acc[mi][nj] = MFMA16(ah[mi], bhv, acc[mi][nj]);
                acc[mi][nj] = MFMA16(al[mi], bhv, acc[mi][nj]);
                acc[mi][nj] = MFMA16(ah[mi], blv, acc[mi][nj]);
            }
        }
        __syncthreads();
    }

    const int g4 = (l >> 4) * 4;
#pragma unroll
    for (int mi = 0; mi < 4; ++mi) {
#pragma unroll
        for (int r = 0; r < 4; ++r) {
            int m = wr * 64 + mi * 16 + g4 + r;
            int p = ps[m];
            if (p < 0) continue;
            int t = p >> 2;
            float wt = wts[m];
            float* dst = out + (size_t)t * D_ + nt * 64 + wc * 32 + (l & 15);
#pragma unroll
            for (int nj = 0; nj < 2; ++nj)
                atomicAdd(dst + nj * 16, wt * acc[mi][nj][r]);
        }
    }
}

// ================= fallback GEMM1 (round-4, proven 220us) =================
__global__ __launch_bounds__(256, 2) void gemm1_mfma(
    const float* __restrict__ x, const float* __restrict__ w1,
    const float* __restrict__ w3, const int* __restrict__ cnt,
    const int* __restrict__ list_p,
    unsigned short* __restrict__ a_hi, unsigned short* __restrict__ a_lo)
{
    const int bid = blockIdx.x;
    const int e   = bid / (MT_TILES * NT1);
    const int rem = bid % (MT_TILES * NT1);
    const int mt  = rem / NT1;
    const int nt  = rem % NT1;
    const int ne  = cnt[e];
    if (mt * BM >= ne) return;
    const int n0  = nt * BN;
    const int tid = threadIdx.x;

    __shared__ int ps[BM];
    __shared__ int ts[BM];
    __shared__ alignas(16) unsigned short Ah[4096], Al[4096];
    __shared__ alignas(16) unsigned short B1h[4096], B1l[4096], B3h[4096], B3l[4096];

    if (tid < BM) {
        int slot = mt * BM + tid;
        if (slot < ne) { int p = list_p[(size_t)e * T_ + slot]; ps[tid] = p; ts[tid] = p >> 2; }
        else           { ps[tid] = -1; ts[tid] = 0; }
    }
    __syncthreads();

    const int qa1 = tid + 256;
    const float* ap0 = x + (size_t)ts[(tid >> 6) * 16 + (tid & 15)] * D_ + ((tid >> 4) & 3) * 8;
    const float* ap1 = x + (size_t)ts[(qa1 >> 6) * 16 + (qa1 & 15)] * D_ + ((qa1 >> 4) & 3) * 8;
    const int offA0 = tid * 8, offA1 = qa1 * 8;

    const int bnf = (tid >> 4) & 7, bcol = tid & 15;
    const int kcb = tid >> 7;
    const size_t wbase = (size_t)e * D_ * H_ + n0 + bnf * 16 + bcol;
    const float* b1p = w1 + wbase;
    const float* b3p = w3 + wbase;
    const int offB0 = (bnf * 64 + kcb * 16 + bcol) * 8;
    const int offB1 = offB0 + 256;

    const int w  = tid >> 6, l = tid & 63;
    const int wr = w >> 1, wc = w & 1;
    const int lo8 = l * 8;

    floatx4 acch[4][4], accg[4][4];
#pragma unroll
    for (int i = 0; i < 4; ++i)
#pragma unroll
        for (int j = 0; j < 4; ++j) { acch[i][j] = (floatx4)0.f; accg[i][j] = (floatx4)0.f; }

    for (int k0 = 0; k0 < D_; k0 += BK) {
        stage_row8(ap0 + k0, Ah + offA0, Al + offA0);
        stage_row8(ap1 + k0, Ah + offA1, Al + offA1);
        stage_w8(b1p, k0 + kcb * 8,       B1h + offB0, B1l + offB0);
        stage_w8(b1p, k0 + (kcb + 2) * 8, B1h + offB1, B1l + offB1);
        stage_w8(b3p, k0 + kcb * 8,       B3h + offB0, B3l + offB0);
        stage_w8(b3p, k0 + (kcb + 2) * 8, B3h + offB1, B3l + offB1);
        __syncthreads();

        short8 ah[4], al[4];
#pragma unroll
        for (int mi = 0; mi < 4; ++mi) {
            int base = (wr * 4 + mi) * 512 + lo8;
            ah[mi] = *reinterpret_cast<const short8*>(Ah + base);
            al[mi] = *reinterpret_cast<const short8*>(Al + base);
        }
#pragma unroll
        for (int nj = 0; nj < 4; ++nj) {
            int bb = (wc * 4 + nj) * 512 + lo8;
            short8 b1hv = *reinterpret_cast<const short8*>(B1h + bb);
            short8 b1lv = *reinterpret_cast<const short8*>(B1l + bb);
            short8 b3hv = *reinterpret_cast<const short8*>(B3h + bb);
            short8 b3lv = *reinterpret_cast<const short8*>(B3l + bb);
#pragma unroll
            for (int mi = 0; mi < 4; ++mi) {
                acch[mi][nj] = MFMA16(ah[mi], b1hv, acch[mi][nj]);
                acch[mi][nj] = MFMA16(al[mi], b1hv, acch[mi][nj]);
                acch[mi][nj] = MFMA16(ah[mi], b1lv, acch[mi][nj]);
                accg[mi][nj] = MFMA16(ah[mi], b3hv, accg[mi][nj]);
                accg[mi][nj] = MFMA16(al[mi], b3hv, accg[mi][nj]);
                accg[mi][nj] = MFMA16(ah[mi], b3lv, accg[mi][nj]);
            }
        }
        __syncthreads();
    }

    const int g4 = (l >> 4) * 4;
#pragma unroll
    for (int mi = 0; mi < 4; ++mi) {
#pragma unroll
        for (int r = 0; r < 4; ++r) {
            int m = wr * 64 + mi * 16 + g4 + r;
            int p = ps[m];
            if (p < 0) continue;
            size_t rowoff = (size_t)p * H_ + n0 + wc * 64 + (l & 15);
#pragma unroll
            for (int nj = 0; nj < 4; ++nj) {
                float h = acch[mi][nj][r];
                float g = accg[mi][nj][r];
                float a = silu_f(h) * g;
                unsigned b = __float_as_uint(a);
                float rr = a - __uint_as_float(b & 0xFFFF0000u);
                a_hi[rowoff + nj * 16] = (unsigned short)(b >> 16);
                a_lo[rowoff + nj * 16] = (unsigned short)(__float_as_uint(rr) >> 16);
            }
        }
    }
}

// ================= fallback GEMM2 (round-4) =================
__global__ __launch_bounds__(256, 2) void gemm2_mfma(
    const unsigned short* __restrict__ a_hi, const unsigned short* __restrict__ a_lo,
    const float* __restrict__ w2, const int* __restrict__ cnt,
    const int* __restrict__ list_p, const float* __restrict__ list_w,
    float* __restrict__ out)
{
    const int bid = blockIdx.x;
    const int e   = bid / (MT_TILES * NT2);
    const int rem = bid % (MT_TILES * NT2);
    const int mt  = rem / NT2;
    const int nt  = rem % NT2;
    const int ne  = cnt[e];
    if (mt * BM >= ne) return;
    const int n0  = nt * BN;
    const int tid = threadIdx.x;

    __shared__ int   ps[BM];
    __shared__ float wts[BM];
    __shared__ int   ats[BM];
    __shared__ alignas(16) unsigned short Ahs[4096], Als[4096], Bh[4096], Bl[4096];

    if (tid < BM) {
        int slot = mt * BM + tid;
        if (slot < ne) {
            int p = list_p[(size_t)e * T_ + slot];
            ps[tid] = p; ats[tid] = p; wts[tid] = list_w[(size_t)e * T_ + slot];
        } else { ps[tid] = -1; ats[tid] = 0; wts[tid] = 0.f; }
    }
    __syncthreads();

    const int qa1 = tid + 256;
    const size_t ar0 = (size_t)ats[(tid >> 6) * 16 + (tid & 15)] * H_ + ((tid >> 4) & 3) * 8;
    const size_t ar1 = (size_t)ats[(qa1 >> 6) * 16 + (qa1 & 15)] * H_ + ((qa1 >> 4) & 3) * 8;
    const int offA0 = tid * 8, offA1 = qa1 * 8;

    const int bnf = (tid >> 4) & 7, bcol = tid & 15;
    const int kcb = tid >> 7;
    const float* b2p = w2 + (size_t)e * H_ * D_ + n0 + bnf * 16 + bcol;
    const int offB0 = (bnf * 64 + kcb * 16 + bcol) * 8;
    const int offB1 = offB0 + 256;

    const int w  = tid >> 6, l = tid & 63;
    const int wr = w >> 1, wc = w & 1;
    const int lo8 = l * 8;

    floatx4 acc[4][4];
#pragma unroll
    for (int i = 0; i < 4; ++i)
#pragma unroll
        for (int j = 0; j < 4; ++j) acc[i][j] = (floatx4)0.f;

    for (int k0 = 0; k0 < H_; k0 += BK) {
        *reinterpret_cast<uint4*>(Ahs + offA0) = *reinterpret_cast<const uint4*>(a_hi + ar0 + k0);
        *reinterpret_cast<uint4*>(Als + offA0) = *reinterpret_cast<const uint4*>(a_lo + ar0 + k0);
        *reinterpret_cast<uint4*>(Ahs + offA1) = *reinterpret_cast<const uint4*>(a_hi + ar1 + k0);
        *reinterpret_cast<uint4*>(Als + offA1) = *reinterpret_cast<const uint4*>(a_lo + ar1 + k0);
        stage_w8(b2p, k0 + kcb * 8,       Bh + offB0, Bl + offB0);
        stage_w8(b2p, k0 + (kcb + 2) * 8, Bh + offB1, Bl + offB1);
        __syncthreads();

        short8 ah[4], al[4];
#pragma unroll
        for (int mi = 0; mi < 4; ++mi) {
            int base = (wr * 4 + mi) * 512 + lo8;
            ah[mi] = *reinterpret_cast<const short8*>(Ahs + base);
            al[mi] = *reinterpret_cast<const short8*>(Als + base);
        }
#pragma unroll
        for (int nj = 0; nj < 4; ++nj) {
            int bb = (wc * 4 + nj) * 512 + lo8;
            short8 bhv = *reinterpret_cast<const short8*>(Bh + bb);
            short8 blv = *reinterpret_cast<const short8*>(Bl + bb);
#pragma unroll
            for (int mi = 0; mi < 4; ++mi) {
                acc[mi][nj] = MFMA16(ah[mi], bhv, acc[mi][nj]);
                acc[mi][nj] = MFMA16(al[mi], bhv, acc[mi][nj]);
                acc[mi][nj] = MFMA16(ah[mi], blv, acc[mi][nj]);
            }
        }
        __syncthreads();
    }

    const int g4 = (l >> 4) * 4;
#pragma unroll
    for (int mi = 0; mi < 4; ++mi) {
#pragma unroll
        for (int r = 0; r < 4; ++r) {
            int m = wr * 64 + mi * 16 + g4 + r;
            int p = ps[m];
            if (p < 0) continue;
            int t = p >> 2;
            float wt = wts[m];
            float* dst = out + (size_t)t * D_ + n0 + wc * 64 + (l & 15);
#pragma unroll
            for (int nj = 0; nj < 4; ++nj)
                atomicAdd(dst + nj * 16, wt * acc[mi][nj][r]);
        }
    }
}

// ================= lb_loss =================
__global__ __launch_bounds__(256) void lb_kernel(
    const float* __restrict__ nsc, const int* __restrict__ cnt, float* __restrict__ out)
{
    const int tid = threadIdx.x;
    float part[E_];
#pragma unroll
    for (int e = 0; e < E_; ++e) part[e] = 0.f;
    for (int t = tid; t < T_; t += 256) {
        const float4* r4 = reinterpret_cast<const float4*>(nsc + (size_t)t * E_);
#pragma unroll
        for (int q = 0; q < 4; ++q) {
            float4 v = r4[q];
            part[q * 4 + 0] += v.x; part[q * 4 + 1] += v.y;
            part[q * 4 + 2] += v.z; part[q * 4 + 3] += v.w;
        }
    }
#pragma unroll
    for (int e = 0; e < E_; ++e) {
        float v = part[e];
#pragma unroll
        for (int off = 32; off > 0; off >>= 1) v += __shfl_down(v, off);
        part[e] = v;
    }
    __shared__ float red[4 * E_];
    const int wave = tid >> 6, lane = tid & 63;
    if (lane == 0) {
#pragma unroll
        for (int e = 0; e < E_; ++e) red[wave * E_ + e] = part[e];
    }
    __syncthreads();
    if (tid == 0) {
        float lb = 0.f;
        for (int e = 0; e < E_; ++e) {
            float s = red[0 * E_ + e] + red[1 * E_ + e] + red[2 * E_ + e] + red[3 * E_ + e];
            lb += ((float)cnt[e] / (float)T_) * (s / (float)T_);
        }
        out[(size_t)T_ * D_] = (float)E_ * lb;
    }
}

// ================= launch =================
extern "C" void kernel_launch(void* const* d_in, const int* in_sizes, int n_in,
                              void* d_out, int out_size, void* d_ws, size_t ws_size,
                              hipStream_t stream)
{
    const float* x    = (const float*)d_in[0];
    const float* gw   = (const float*)d_in[1];
    const float* bias = (const float*)d_in[2];
    const float* w1   = (const float*)d_in[3];
    const float* w3   = (const float*)d_in[4];
    const float* w2   = (const float*)d_in[5];
    float* out = (float*)d_out;
    char*  ws  = (char*)d_ws;

    hipMemsetAsync(d_out, 0, (size_t)out_size * sizeof(float), stream);
    hipMemsetAsync(ws, 0, 256, stream);   // cnt

    const bool fast = (ws_size >= FWS_NEED);

    if (fast) {
        int*   cnt    = (int*)  (ws + FWS_CNT);
        int*   list_p = (int*)  (ws + FWS_LISTP);
        float* list_w = (float*)(ws + FWS_LISTW);
        float* nsc    = (float*)(ws + FWS_NSC);
        unsigned short* xhi  = (unsigned short*)(ws + FWS_XHI);
        unsigned short* xlo  = (unsigned short*)(ws + FWS_XLO);
        unsigned short* a_hi = (unsigned short*)(ws + FWS_AHI);
        unsigned short* a_lo = (unsigned short*)(ws + FWS_ALO);
        unsigned short* w1s  = (unsigned short*)(ws + FWS_W1S);
        unsigned short* w3s  = (unsigned short*)(ws + FWS_W3S);
        unsigned short* w2s  = (unsigned short*)(ws + FWS_W2S);

        conv_w<<<3 * 8192, 256, 0, stream>>>(w1, w3, w2, w1s, w3s, w2s);
        conv_x<<<T_ * D_ / (256 * 8), 256, 0, stream>>>(x, xhi, xlo);
        router_kernel<<<T_, 256, 0, stream>>>(x, gw, bias, cnt, nsc, list_p, list_w);
        gemm1_fast<<<E_ * FMT * FNT, 256, 0, stream>>>(xhi, xlo, w1s, w3s, cnt, list_p, a_hi, a_lo);
        gemm2_fast<<<E_ * FMT * FNT, 256, 0, stream>>>(a_hi, a_lo, w2s, cnt, list_p, list_w, out);
        lb_kernel<<<1, 256, 0, stream>>>(nsc, cnt, out);
    } else {
        int*   cnt    = (int*)  (ws + WS_CNT);
        int*   list_p = (int*)  (ws + WS_LISTP);
        float* list_w = (float*)(ws + WS_LISTW);
        float* nsc    = (float*)(ws + WS_NSC);
        unsigned short* a_hi = (unsigned short*)(ws + WS_AHI);
        unsigned short* a_lo = (unsigned short*)(ws + WS_ALO);

        router_kernel<<<T_, 256, 0, stream>>>(x, gw, bias, cnt, nsc, list_p, list_w);
        gemm1_mfma<<<E_ * MT_TILES * NT1, 256, 0, stream>>>(x, w1, w3, cnt, list_p, a_hi, a_lo);
        gemm2_mfma<<<E_ * MT_TILES * NT2, 256, 0, stream>>>(a_hi, a_lo, w2, cnt, list_p, list_w, out);
        lb_kernel<<<1, 256, 0, stream>>>(nsc, cnt, out);
    }
}

// Round 7
// 577.137 us; speedup vs baseline: 2.0826x; 1.0270x over previous
//
#include <hip/hip_runtime.h>
#include <math.h>

// ---------------- problem constants ----------------
constexpr int T_ = 2048;   // tokens (B*S)
constexpr int D_ = 1024;   // model dim
constexpr int E_ = 16;     // experts
constexpr int H_ = 1024;   // expert hidden
constexpr int K_ = 4;      // top-k
constexpr float EPS_ = 1e-6f;

// ---------------- tiling: BM=128, BN=128, BK=32, 4 waves (2x2), wave tile 64x64 ----
constexpr int FMT = 16;      // worst-case M-tiles (T*K/128 all on one expert)
constexpr int NTB = 8;       // N-tiles of 128 over 1024

// ---------------- workspace layout (bytes) ----------------
constexpr size_t FWS_CNT   = 0;                                   // E ints
constexpr size_t FWS_LISTP = 256;
constexpr size_t FWS_LISTW = FWS_LISTP + (size_t)E_ * T_ * 4;
constexpr size_t FWS_NSC   = FWS_LISTW + (size_t)E_ * T_ * 4;
constexpr size_t FWS_XHI   = FWS_NSC  + (size_t)T_ * E_ * 4;      // T*D shorts
constexpr size_t FWS_XLO   = FWS_XHI  + (size_t)T_ * D_ * 2;
constexpr size_t FWS_AHI   = FWS_XLO  + (size_t)T_ * D_ * 2;      // T*K*H shorts
constexpr size_t FWS_ALO   = FWS_AHI  + (size_t)T_ * K_ * H_ * 2;
constexpr size_t FWS_W1S   = FWS_ALO  + (size_t)T_ * K_ * H_ * 2; // swizzled hi/lo
constexpr size_t FWS_W3S   = FWS_W1S  + (size_t)E_ * D_ * H_ * 4;
constexpr size_t FWS_W2S   = FWS_W3S  + (size_t)E_ * D_ * H_ * 4;
constexpr size_t FWS_NEED  = FWS_W2S  + (size_t)E_ * H_ * D_ * 4; // ~232 MB (proven to fit r5)

using short8  = __attribute__((ext_vector_type(8))) short;
using floatx4 = __attribute__((ext_vector_type(4))) float;

#define MFMA16(a, b, c) __builtin_amdgcn_mfma_f32_16x16x32_bf16((a), (b), (c), 0, 0, 0)

__device__ __forceinline__ float silu_f(float h) {
    return h / (1.f + expf(-h));
}

// async 16B global->LDS (per-lane global src; LDS dest = wave base + lane*16)
__device__ __forceinline__ void gll16(const void* g, void* l) {
    __builtin_amdgcn_global_load_lds(
        (const __attribute__((address_space(1))) unsigned int*)g,
        (__attribute__((address_space(3))) unsigned int*)l, 16, 0, 0);
}

// split fp32 -> bf16 hi (truncate) + bf16 lo (truncated residual)
__device__ __forceinline__ void pack_split8(const float f[8], unsigned short* dh, unsigned short* dl) {
    unsigned hb[8], lb[8];
#pragma unroll
    for (int i = 0; i < 8; ++i) {
        unsigned b = __float_as_uint(f[i]);
        float hf = __uint_as_float(b & 0xFFFF0000u);
        float r = f[i] - hf;
        hb[i] = b >> 16;
        lb[i] = __float_as_uint(r) >> 16;
    }
    uint4 hv, lv;
    hv.x = hb[0] | (hb[1] << 16); hv.y = hb[2] | (hb[3] << 16);
    hv.z = hb[4] | (hb[5] << 16); hv.w = hb[6] | (hb[7] << 16);
    lv.x = lb[0] | (lb[1] << 16); lv.y = lb[2] | (lb[3] << 16);
    lv.z = lb[4] | (lb[5] << 16); lv.w = lb[6] | (lb[7] << 16);
    *reinterpret_cast<uint4*>(dh) = hv;
    *reinterpret_cast<uint4*>(dl) = lv;
}

// ================= router =================
__global__ __launch_bounds__(256) void router_kernel(
    const float* __restrict__ x, const float* __restrict__ gw,
    const float* __restrict__ bias,
    int* __restrict__ cnt, float* __restrict__ nsc,
    int* __restrict__ list_p, float* __restrict__ list_w)
{
    const int t = blockIdx.x;
    const int tid = threadIdx.x;

    float part[E_];
#pragma unroll
    for (int e = 0; e < E_; ++e) part[e] = 0.f;

    const float* xr = x + (size_t)t * D_;
    for (int it = 0; it < D_ / 256; ++it) {
        int d = it * 256 + tid;
        float xv = xr[d];
        const float4* g4 = reinterpret_cast<const float4*>(gw + (size_t)d * E_);
#pragma unroll
        for (int q = 0; q < 4; ++q) {
            float4 gv = g4[q];
            part[q * 4 + 0] += xv * gv.x;
            part[q * 4 + 1] += xv * gv.y;
            part[q * 4 + 2] += xv * gv.z;
            part[q * 4 + 3] += xv * gv.w;
        }
    }
#pragma unroll
    for (int e = 0; e < E_; ++e) {
        float v = part[e];
#pragma unroll
        for (int off = 32; off > 0; off >>= 1) v += __shfl_down(v, off);
        part[e] = v;
    }
    __shared__ float red[4 * E_];
    const int wave = tid >> 6, lane = tid & 63;
    if (lane == 0) {
#pragma unroll
        for (int e = 0; e < E_; ++e) red[wave * E_ + e] = part[e];
    }
    __syncthreads();

    __shared__ float sc[E_];
    if (tid < E_) {
        float s = red[0 * E_ + tid] + red[1 * E_ + tid] + red[2 * E_ + tid] + red[3 * E_ + tid];
        s += bias[tid];
        sc[tid] = 1.f / (1.f + expf(-s));
    }
    __syncthreads();

    if (tid == 0) {
        float sum = 0.f;
#pragma unroll
        for (int e = 0; e < E_; ++e) sum += sc[e];
        float den = sum + EPS_;
        float ns[E_];
#pragma unroll
        for (int e = 0; e < E_; ++e) {
            ns[e] = sc[e] / den;
            nsc[(size_t)t * E_ + e] = ns[e];
        }
        bool used[E_];
#pragma unroll
        for (int e = 0; e < E_; ++e) used[e] = false;
        int sel[K_]; float selw[K_]; float wsum = 0.f;
        for (int k = 0; k < K_; ++k) {
            float best = -1.f; int bi = 0;
            for (int e = 0; e < E_; ++e)
                if (!used[e] && ns[e] > best) { best = ns[e]; bi = e; }
            used[bi] = true; sel[k] = bi; selw[k] = best; wsum += best;
        }
        float wden = wsum + EPS_;
        for (int k = 0; k < K_; ++k) {
            int e = sel[k];
            int slot = atomicAdd(&cnt[e], 1);
            list_p[(size_t)e * T_ + slot] = t * K_ + k;
            list_w[(size_t)e * T_ + slot] = selw[k] / wden;
        }
    }
}

// ================= weight conversion =================
// w[e][k][n] fp32 -> per-(e,nt64,ks) 8KB block: 2048 shorts hi ++ 2048 lo.
// run r' = (nf*4+kc)*16+col (nf<4), element j = w[ks*32+kc*8+j][nt*64+nf*16+col]
__global__ __launch_bounds__(256) void conv_w(
    const float* __restrict__ w1, const float* __restrict__ w3, const float* __restrict__ w2,
    unsigned short* __restrict__ d1, unsigned short* __restrict__ d3, unsigned short* __restrict__ d2)
{
    const int b = blockIdx.x;
    const int wsel = b >> 13;          // 8192 blocks per weight
    const int rem = b & 8191;
    const int e = rem >> 9;
    const int rem2 = rem & 511;
    const int nt = rem2 >> 5;
    const int ks = rem2 & 31;
    const int tid = threadIdx.x;

    const float* src = (wsel == 0 ? w1 : wsel == 1 ? w3 : w2)
                     + ((size_t)e * 1024 + ks * 32) * 1024 + nt * 64;
    unsigned short* dst = (wsel == 0 ? d1 : wsel == 1 ? d3 : d2)
                        + ((size_t)(e * 16 + nt) * 32 + ks) * 4096;

    __shared__ float tile[32][65];
    const int r = tid >> 3, c0 = (tid & 7) * 8;
    float4 v0 = *reinterpret_cast<const float4*>(src + (size_t)r * 1024 + c0);
    float4 v1 = *reinterpret_cast<const float4*>(src + (size_t)r * 1024 + c0 + 4);
    tile[r][c0 + 0] = v0.x; tile[r][c0 + 1] = v0.y; tile[r][c0 + 2] = v0.z; tile[r][c0 + 3] = v0.w;
    tile[r][c0 + 4] = v1.x; tile[r][c0 + 5] = v1.y; tile[r][c0 + 6] = v1.z; tile[r][c0 + 7] = v1.w;
    __syncthreads();

    const int nf = tid >> 6, kc = (tid >> 4) & 3, col = tid & 15;
    float f[8];
#pragma unroll
    for (int j = 0; j < 8; ++j) f[j] = tile[kc * 8 + j][nf * 16 + col];
    pack_split8(f, dst + tid * 8, dst + 2048 + tid * 8);
}

// x -> hi/lo planes (row-major [t][d] shorts)
__global__ __launch_bounds__(256) void conv_x(
    const float* __restrict__ x, unsigned short* __restrict__ xhi, unsigned short* __restrict__ xlo)
{
    const size_t i = ((size_t)blockIdx.x * 256 + threadIdx.x) * 8;
    float4 a = *reinterpret_cast<const float4*>(x + i);
    float4 b = *reinterpret_cast<const float4*>(x + i + 4);
    float f[8] = {a.x, a.y, a.z, a.w, b.x, b.y, b.z, b.w};
    pack_split8(f, xhi + i, xlo + i);
}

// ================= GEMM1: a = silu(x@w1)*(x@w3) =================
// BM=128, BN=128, BK=32; 4 waves (2x2); wave tile 64x64; gll16 staging.
__global__ __launch_bounds__(256, 2) void gemm1_fast(
    const unsigned short* __restrict__ xhi, const unsigned short* __restrict__ xlo,
    const unsigned short* __restrict__ w1s, const unsigned short* __restrict__ w3s,
    const int* __restrict__ cnt, const int* __restrict__ list_p,
    unsigned short* __restrict__ a_hi, unsigned short* __restrict__ a_lo)
{
    // bijective XCD swizzle over 2048 blocks (2048 % 8 == 0)
    const int bid0 = blockIdx.x;
    const int bid  = (bid0 & 7) * 256 + (bid0 >> 3);
    const int e   = bid >> 7;          // 128 blocks/expert
    const int rem = bid & 127;
    const int mt  = rem >> 3;          // 16 m-tiles
    const int ntb = rem & 7;           // 8 n-tiles of 128
    const int ne  = cnt[e];
    if (mt * 128 >= ne) return;
    const int tid = threadIdx.x;

    __shared__ int ps[128];
    __shared__ int ts[128];
    __shared__ alignas(16) unsigned short Ah[4096], Al[4096];                   // 128x32
    __shared__ alignas(16) unsigned short B1h[4096], B1l[4096];                 // 32x128
    __shared__ alignas(16) unsigned short B3h[4096], B3l[4096];

    if (tid < 128) {
        int slot = mt * 128 + tid;
        if (slot < ne) { int p = list_p[(size_t)e * T_ + slot]; ps[tid] = p; ts[tid] = p >> 2; }
        else           { ps[tid] = -1; ts[tid] = 0; }
    }
    __syncthreads();

    // A gather: runs tid (mf 0..3) and tid+256 (mf 4..7); run R: mf=R>>6, kc=(R>>4)&3, r16=R&15
    const int mf0 = tid >> 6, kc0 = (tid >> 4) & 3, r16 = tid & 15;
    const unsigned short* axh0 = xhi + (size_t)ts[mf0 * 16 + r16] * D_ + kc0 * 8;
    const unsigned short* axl0 = xlo + (size_t)ts[mf0 * 16 + r16] * D_ + kc0 * 8;
    const unsigned short* axh1 = xhi + (size_t)ts[(mf0 + 4) * 16 + r16] * D_ + kc0 * 8;
    const unsigned short* axl1 = xlo + (size_t)ts[(mf0 + 4) * 16 + r16] * D_ + kc0 * 8;

    // B: two adjacent 64-col source blocks per 128-tile; within-block run index == tid
    const unsigned short* b1a = w1s + ((size_t)(e * 16 + ntb * 2)     * 32) * 4096 + tid * 8;
    const unsigned short* b1b = w1s + ((size_t)(e * 16 + ntb * 2 + 1) * 32) * 4096 + tid * 8;
    const unsigned short* b3a = w3s + ((size_t)(e * 16 + ntb * 2)     * 32) * 4096 + tid * 8;
    const unsigned short* b3b = w3s + ((size_t)(e * 16 + ntb * 2 + 1) * 32) * 4096 + tid * 8;

    const int w = tid >> 6, l = tid & 63;
    const int wr = w >> 1, wc = w & 1;
    const int lo8 = l * 8;

    floatx4 acch[4][4], accg[4][4];
#pragma unroll
    for (int i = 0; i < 4; ++i)
#pragma unroll
        for (int j = 0; j < 4; ++j) { acch[i][j] = (floatx4)0.f; accg[i][j] = (floatx4)0.f; }

    for (int k0 = 0; k0 < D_; k0 += 32) {
        const int ksoff = (k0 >> 5) * 4096;
        gll16(axh0 + k0, Ah + tid * 8);
        gll16(axh1 + k0, Ah + (tid + 256) * 8);
        gll16(axl0 + k0, Al + tid * 8);
        gll16(axl1 + k0, Al + (tid + 256) * 8);
        gll16(b1a + ksoff,        B1h + tid * 8);
        gll16(b1b + ksoff,        B1h + (tid + 256) * 8);
        gll16(b1a + ksoff + 2048, B1l + tid * 8);
        gll16(b1b + ksoff + 2048, B1l + (tid + 256) * 8);
        gll16(b3a + ksoff,        B3h + tid * 8);
        gll16(b3b + ksoff,        B3h + (tid + 256) * 8);
        gll16(b3a + ksoff + 2048, B3l + tid * 8);
        gll16(b3b + ksoff + 2048, B3l + (tid + 256) * 8);
        __syncthreads();

        short8 ah[4], al[4];
#pragma unroll
        for (int mi = 0; mi < 4; ++mi) {
            int base = (wr * 4 + mi) * 512 + lo8;
            ah[mi] = *reinterpret_cast<const short8*>(Ah + base);
            al[mi] = *reinterpret_cast<const short8*>(Al + base);
        }
#pragma unroll
        for (int nj = 0; nj < 4; ++nj) {
            int bb = (wc * 4 + nj) * 512 + lo8;
            short8 b1hv = *reinterpret_cast<const short8*>(B1h + bb);
            short8 b1lv = *reinterpret_cast<const short8*>(B1l + bb);
            short8 b3hv = *reinterpret_cast<const short8*>(B3h + bb);
            short8 b3lv = *reinterpret_cast<const short8*>(B3l + bb);
#pragma unroll
            for (int mi = 0; mi < 4; ++mi) {
                acch[mi][nj] = MFMA16(ah[mi], b1hv, acch[mi][nj]);
                acch[mi][nj] = MFMA16(al[mi], b1hv, acch[mi][nj]);
                acch[mi][nj] = MFMA16(ah[mi], b1lv, acch[mi][nj]);
                accg[mi][nj] = MFMA16(ah[mi], b3hv, accg[mi][nj]);
                accg[mi][nj] = MFMA16(al[mi], b3hv, accg[mi][nj]);
                accg[mi][nj] = MFMA16(ah[mi], b3lv, accg[mi][nj]);
            }
        }
        __syncthreads();
    }

    // epilogue: C/D map col=l&15, row=(l>>4)*4+r
    const int g4 = (l >> 4) * 4;
#pragma unroll
    for (int mi = 0; mi < 4; ++mi) {
#pragma unroll
        for (int r = 0; r < 4; ++r) {
            int m = wr * 64 + mi * 16 + g4 + r;
            int p = ps[m];
            if (p < 0) continue;
            size_t ro = (size_t)p * H_ + ntb * 128 + wc * 64 + (l & 15);
#pragma unroll
            for (int nj = 0; nj < 4; ++nj) {
                float h = acch[mi][nj][r];
                float g = accg[mi][nj][r];
                float a = silu_f(h) * g;
                unsigned b = __float_as_uint(a);
                float rr = a - __uint_as_float(b & 0xFFFF0000u);
                a_hi[ro + nj * 16] = (unsigned short)(b >> 16);
                a_lo[ro + nj * 16] = (unsigned short)(__float_as_uint(rr) >> 16);
            }
        }
    }
}

// ================= GEMM2: out[t] += wt * (a[p] @ w2[e]) =================
__global__ __launch_bounds__(256, 3) void gemm2_fast(
    const unsigned short* __restrict__ a_hi, const unsigned short* __restrict__ a_lo,
    const unsigned short* __restrict__ w2s, const int* __restrict__ cnt,
    const int* __restrict__ list_p, const float* __restrict__ list_w,
    float* __restrict__ out)
{
    const int bid0 = blockIdx.x;
    const int bid  = (bid0 & 7) * 256 + (bid0 >> 3);
    const int e   = bid >> 7;
    const int rem = bid & 127;
    const int mt  = rem >> 3;
    const int ntb = rem & 7;
    const int ne  = cnt[e];
    if (mt * 128 >= ne) return;
    const int tid = threadIdx.x;

    __shared__ int   ps[128];
    __shared__ float wts[128];
    __shared__ alignas(16) unsigned short Ahs[4096], Als[4096];
    __shared__ alignas(16) unsigned short Bh[4096], Bl[4096];

    if (tid < 128) {
        int slot = mt * 128 + tid;
        if (slot < ne) {
            int p = list_p[(size_t)e * T_ + slot];
            ps[tid] = p; wts[tid] = list_w[(size_t)e * T_ + slot];
        } else { ps[tid] = -1; wts[tid] = 0.f; }
    }
    __syncthreads();

    const int mf0 = tid >> 6, kc0 = (tid >> 4) & 3, r16 = tid & 15;
    int p0 = ps[mf0 * 16 + r16];      if (p0 < 0) p0 = 0;
    int p1 = ps[mf0 * 16 + 64 + r16]; if (p1 < 0) p1 = 0;
    const unsigned short* aah0 = a_hi + (size_t)p0 * H_ + kc0 * 8;
    const unsigned short* aal0 = a_lo + (size_t)p0 * H_ + kc0 * 8;
    const unsigned short* aah1 = a_hi + (size_t)p1 * H_ + kc0 * 8;
    const unsigned short* aal1 = a_lo + (size_t)p1 * H_ + kc0 * 8;

    const unsigned short* b2a = w2s + ((size_t)(e * 16 + ntb * 2)     * 32) * 4096 + tid * 8;
    const unsigned short* b2b = w2s + ((size_t)(e * 16 + ntb * 2 + 1) * 32) * 4096 + tid * 8;

    const int w = tid >> 6, l = tid & 63;
    const int wr = w >> 1, wc = w & 1;
    const int lo8 = l * 8;

    floatx4 acc[4][4];
#pragma unroll
    for (int i = 0; i < 4; ++i)
#pragma unroll
        for (int j = 0; j < 4; ++j) acc[i][j] = (floatx4)0.f;

    for (int k0 = 0; k0 < H_; k0 += 32) {
        const int ksoff = (k0 >> 5) * 4096;
        gll16(aah0 + k0, Ahs + tid * 8);
        gll16(aah1 + k0, Ahs + (tid + 256) * 8);
        gll16(aal0 + k0, Als + tid * 8);
        gll16(aal1 + k0, Als + (tid + 256) * 8);
        gll16(b2a + ksoff,        Bh + tid * 8);
        gll16(b2b + ksoff,        Bh + (tid + 256) * 8);
        gll16(b2a + ksoff + 2048, Bl + tid * 8);
        gll16(b2b + ksoff + 2048, Bl + (tid + 256) * 8);
        __syncthreads();

        short8 ah[4], al[4];
#pragma unroll
        for (int mi = 0; mi < 4; ++mi) {
            int base = (wr * 4 + mi) * 512 + lo8;
            ah[mi] = *reinterpret_cast<const short8*>(Ahs + base);
            al[mi] = *reinterpret_cast<const short8*>(Als + base);
        }
#pragma unroll
        for (int nj = 0; nj < 4; ++nj) {
            int bb = (wc * 4 + nj) * 512 + lo8;
            short8 bhv = *reinterpret_cast<const short8*>(Bh + bb);
            short8 blv = *reinterpret_cast<const short8*>(Bl + bb);
#pragma unroll
            for (int mi = 0; mi < 4; ++mi) {
                acc[mi][nj] = MFMA16(ah[mi], bhv, acc[mi][nj]);
                acc[mi][nj] = MFMA16(al[mi], bhv, acc[mi][nj]);
                acc[mi][nj] = MFMA16(ah[mi], blv, acc[mi][nj]);
            }
        }
        __syncthreads();
    }

    const int g4 = (l >> 4) * 4;
#pragma unroll
    for (int mi = 0; mi < 4; ++mi) {
#pragma unroll
        for (int r = 0; r < 4; ++r) {
            int m = wr * 64 + mi * 16 + g4 + r;
            int p = ps[m];
            if (p < 0) continue;
            int t = p >> 2;
            float wt = wts[m];
            float* dst = out + (size_t)t * D_ + ntb * 128 + wc * 64 + (l & 15);
#pragma unroll
            for (int nj = 0; nj < 4; ++nj)
                atomicAdd(dst + nj * 16, wt * acc[mi][nj][r]);
        }
    }
}

// ================= lb_loss =================
__global__ __launch_bounds__(256) void lb_kernel(
    const float* __restrict__ nsc, const int* __restrict__ cnt, float* __restrict__ out)
{
    const int tid = threadIdx.x;
    float part[E_];
#pragma unroll
    for (int e = 0; e < E_; ++e) part[e] = 0.f;
    for (int t = tid; t < T_; t += 256) {
        const float4* r4 = reinterpret_cast<const float4*>(nsc + (size_t)t * E_);
#pragma unroll
        for (int q = 0; q < 4; ++q) {
            float4 v = r4[q];
            part[q * 4 + 0] += v.x; part[q * 4 + 1] += v.y;
            part[q * 4 + 2] += v.z; part[q * 4 + 3] += v.w;
        }
    }
#pragma unroll
    for (int e = 0; e < E_; ++e) {
        float v = part[e];
#pragma unroll
        for (int off = 32; off > 0; off >>= 1) v += __shfl_down(v, off);
        part[e] = v;
    }
    __shared__ float red[4 * E_];
    const int wave = tid >> 6, lane = tid & 63;
    if (lane == 0) {
#pragma unroll
        for (int e = 0; e < E_; ++e) red[wave * E_ + e] = part[e];
    }
    __syncthreads();
    if (tid == 0) {
        float lb = 0.f;
        for (int e = 0; e < E_; ++e) {
            float s = red[0 * E_ + e] + red[1 * E_ + e] + red[2 * E_ + e] + red[3 * E_ + e];
            lb += ((float)cnt[e] / (float)T_) * (s / (float)T_);
        }
        out[(size_t)T_ * D_] = (float)E_ * lb;
    }
}

// ================= launch =================
extern "C" void kernel_launch(void* const* d_in, const int* in_sizes, int n_in,
                              void* d_out, int out_size, void* d_ws, size_t ws_size,
                              hipStream_t stream)
{
    const float* x    = (const float*)d_in[0];
    const float* gw   = (const float*)d_in[1];
    const float* bias = (const float*)d_in[2];
    const float* w1   = (const float*)d_in[3];
    const float* w3   = (const float*)d_in[4];
    const float* w2   = (const float*)d_in[5];
    float* out = (float*)d_out;
    char*  ws  = (char*)d_ws;

    int*   cnt    = (int*)  (ws + FWS_CNT);
    int*   list_p = (int*)  (ws + FWS_LISTP);
    float* list_w = (float*)(ws + FWS_LISTW);
    float* nsc    = (float*)(ws + FWS_NSC);
    unsigned short* xhi  = (unsigned short*)(ws + FWS_XHI);
    unsigned short* xlo  = (unsigned short*)(ws + FWS_XLO);
    unsigned short* a_hi = (unsigned short*)(ws + FWS_AHI);
    unsigned short* a_lo = (unsigned short*)(ws + FWS_ALO);
    unsigned short* w1s  = (unsigned short*)(ws + FWS_W1S);
    unsigned short* w3s  = (unsigned short*)(ws + FWS_W3S);
    unsigned short* w2s  = (unsigned short*)(ws + FWS_W2S);

    hipMemsetAsync(d_out, 0, (size_t)out_size * sizeof(float), stream);
    hipMemsetAsync(ws, 0, 256, stream);   // cnt

    conv_w<<<3 * 8192, 256, 0, stream>>>(w1, w3, w2, w1s, w3s, w2s);
    conv_x<<<T_ * D_ / (256 * 8), 256, 0, stream>>>(x, xhi, xlo);
    router_kernel<<<T_, 256, 0, stream>>>(x, gw, bias, cnt, nsc, list_p, list_w);
    gemm1_fast<<<E_ * FMT * NTB, 256, 0, stream>>>(xhi, xlo, w1s, w3s, cnt, list_p, a_hi, a_lo);
    gemm2_fast<<<E_ * FMT * NTB, 256, 0, stream>>>(a_hi, a_lo, w2s, cnt, list_p, list_w, out);
    lb_kernel<<<1, 256, 0, stream>>>(nsc, cnt, out);
}